// Round 1
// baseline (4128.515 us; speedup 1.0000x reference)
//
#include <hip/hip_runtime.h>
#include <hip/hip_bf16.h>
#include <math.h>

#define N_ATOMS 20000
#define N_EDGES 320000
#define FEAT 128
#define N_RBF 20
#define N_CONV 3
#define ATOM_FEA_ 64
#define H_FEA_ 128
#define N_OUT_ 5
#define PI_F 3.14159265358979f

// ---------------- workspace layout (in floats) ----------------
constexpr size_t rnd64(size_t x){ return (x + 63) & ~size_t(63); }
constexpr size_t A_XYZ   = 64;                                   // flag lives at ws[0]
constexpr size_t A_EMBED = rnd64(A_XYZ   + 60000);
constexpr size_t A_W1    = rnd64(A_EMBED + 12800);
constexpr size_t A_B1    = rnd64(A_W1    + 3*128*128);
constexpr size_t A_W2    = rnd64(A_B1    + 3*128);
constexpr size_t A_B2    = rnd64(A_W2    + 3*128*384);
constexpr size_t A_WD    = rnd64(A_B2    + 3*384);
constexpr size_t A_BD    = rnd64(A_WD    + 3*20*384);
constexpr size_t A_U     = rnd64(A_BD    + 3*384);
constexpr size_t A_V     = rnd64(A_U     + 3*128*128);
constexpr size_t A_WS1   = rnd64(A_V     + 3*128*128);
constexpr size_t A_BS1   = rnd64(A_WS1   + 3*256*128);
constexpr size_t A_WS2   = rnd64(A_BS1   + 3*128);
constexpr size_t A_BS2   = rnd64(A_WS2   + 3*128*384);
constexpr size_t A_WR1   = rnd64(A_BS2   + 3*384);
constexpr size_t A_BR1   = rnd64(A_WR1   + 128*128);
constexpr size_t A_WR2   = rnd64(A_BR1   + 128);
constexpr size_t A_BR2   = rnd64(A_WR2   + 128*64);
constexpr size_t A_WF1   = rnd64(A_BR2   + 64);
constexpr size_t A_BF1   = rnd64(A_WF1   + 64*128);
constexpr size_t A_WF2   = rnd64(A_BF1   + 128);
constexpr size_t A_BF2   = rnd64(A_WF2   + 128*128);
constexpr size_t A_WF3   = rnd64(A_BF2   + 128);
constexpr size_t A_BF3   = rnd64(A_WF3   + 128*5);
constexpr size_t A_D     = rnd64(A_BF3   + 5);
constexpr size_t A_UNIT  = rnd64(A_D     + N_EDGES);
constexpr size_t A_SA    = rnd64(A_UNIT  + 3*N_EDGES);
constexpr size_t A_SB    = rnd64(A_SA    + (size_t)N_ATOMS*FEAT);
constexpr size_t A_VA    = rnd64(A_SB    + (size_t)N_ATOMS*FEAT);
constexpr size_t A_VB    = rnd64(A_VA    + (size_t)N_ATOMS*3*FEAT);
constexpr size_t A_PHIH  = rnd64(A_VB    + (size_t)N_ATOMS*3*FEAT);   // 20000x128 (alias h1/t1/h2)
constexpr size_t A_PHI   = rnd64(A_PHIH  + (size_t)N_ATOMS*FEAT);     // 20000x384 (alias uv, h)
constexpr size_t A_VV    = rnd64(A_PHI   + (size_t)N_ATOMS*3*FEAT);
constexpr size_t A_SPLIT = rnd64(A_VV    + (size_t)N_ATOMS*3*FEAT);
constexpr size_t A_CAT   = rnd64(A_SPLIT + (size_t)N_ATOMS*3*FEAT);   // 20000x256 (alias atom_fea)
constexpr size_t A_OUTF  = rnd64(A_CAT   + (size_t)N_ATOMS*2*FEAT);

// ---------------- dtype detection ----------------
// bf16 pair read as u32: low 16 bits are a bf16 of uniform[0,4) -> in [0x3000,0x4100]
// f32: low 16 bits are uniform mantissa bits -> ~6.6% in window.
__global__ void k_detect(const unsigned int* __restrict__ bits, int* flag){
    __shared__ int cnt;
    if (threadIdx.x == 0) cnt = 0;
    __syncthreads();
    unsigned int w  = bits[threadIdx.x];
    unsigned int lo = w & 0xFFFFu;
    if (lo >= 0x3000u && lo <= 0x4100u) atomicAdd(&cnt, 1);
    __syncthreads();
    if (threadIdx.x == 0) *flag = (cnt >= 48) ? 1 : 0;
}

__global__ void k_cvt(const void* __restrict__ src, float* __restrict__ dst, int n,
                      const int* __restrict__ flag){
    int t = blockIdx.x * blockDim.x + threadIdx.x;
    if (t >= n) return;
    if (*flag) {
        unsigned int w = ((unsigned int)((const unsigned short*)src)[t]) << 16;
        dst[t] = __uint_as_float(w);
    } else {
        dst[t] = ((const float*)src)[t];
    }
}

__global__ void k_store_out(const float* __restrict__ src, void* __restrict__ dst, int n,
                            const int* __restrict__ flag){
    int t = blockIdx.x * blockDim.x + threadIdx.x;
    if (t >= n) return;
    float v = src[t];
    if (*flag) ((__hip_bfloat16*)dst)[t] = __float2bfloat16(v);
    else       ((float*)dst)[t] = v;
}

// ---------------- small utility kernels ----------------
__global__ void k_zero(float* p, int n){
    int t = blockIdx.x * blockDim.x + threadIdx.x;
    if (t < n) p[t] = 0.f;
}
__global__ void k_copy(float* __restrict__ dst, const float* __restrict__ src, int n){
    int t = blockIdx.x * blockDim.x + threadIdx.x;
    if (t < n) dst[t] = src[t];
}
__global__ void k_init_s(const float* __restrict__ embed, const int* __restrict__ z,
                         float* __restrict__ s){
    int t = blockIdx.x * blockDim.x + threadIdx.x;
    if (t >= N_ATOMS * FEAT) return;
    int n = t >> 7, f = t & 127;
    s[t] = embed[z[n] * FEAT + f];
}

// ---------------- edge geometry ----------------
__global__ void k_geom(const float* __restrict__ xyz, const int* __restrict__ nbrs,
                       float* __restrict__ dbuf, float* __restrict__ unit){
    int e = blockIdx.x * blockDim.x + threadIdx.x;
    if (e >= N_EDGES) return;
    int i = nbrs[2*e], j = nbrs[2*e+1];
    float rx = xyz[3*j]   - xyz[3*i];
    float ry = xyz[3*j+1] - xyz[3*i+1];
    float rz = xyz[3*j+2] - xyz[3*i+2];
    float d  = sqrtf(rx*rx + ry*ry + rz*rz + 1e-12f);
    dbuf[e] = d;
    float inv = 1.0f / d;
    unit[3*e] = rx*inv; unit[3*e+1] = ry*inv; unit[3*e+2] = rz*inv;
}

// ---------------- generic tiled GEMM: C = act(A @ B + bias) ----------------
// A: MxK row-major, B: KxN row-major, C: MxN. act: 0=none, 1=silu
__global__ void k_gemm(const float* __restrict__ A, const float* __restrict__ B,
                       const float* __restrict__ bias, float* __restrict__ C,
                       int M, int K, int N, int act){
    __shared__ float As[16][17];
    __shared__ float Bs[16][17];
    int ty = threadIdx.y, tx = threadIdx.x;
    int row = blockIdx.y * 16 + ty;
    int col = blockIdx.x * 16 + tx;
    float acc = 0.f;
    for (int k0 = 0; k0 < K; k0 += 16) {
        int ka = k0 + tx, kb = k0 + ty;
        As[ty][tx] = (row < M && ka < K) ? A[(size_t)row * K + ka] : 0.f;
        Bs[ty][tx] = (kb < K && col < N) ? B[(size_t)kb * N + col] : 0.f;
        __syncthreads();
        #pragma unroll
        for (int kk = 0; kk < 16; kk++) acc += As[ty][kk] * Bs[kk][tx];
        __syncthreads();
    }
    if (row < M && col < N) {
        if (bias) acc += bias[col];
        if (act)  acc = acc / (1.f + expf(-acc));
        C[(size_t)row * N + col] = acc;
    }
}

// ---------------- edge message + scatter ----------------
// block = 128 threads = one edge; thread f handles feature channel f.
// w_s computed on the fly from rbf (in LDS) and Wd/bd; scatter via atomics.
__global__ void k_edge(const float* __restrict__ phi, const float* __restrict__ v_in,
                       const float* __restrict__ unit, const float* __restrict__ dbuf,
                       const int* __restrict__ nbrs,
                       const float* __restrict__ Wd, const float* __restrict__ bd,
                       float* __restrict__ s_out, float* __restrict__ v_out){
    int e = blockIdx.x;
    int f = threadIdx.x;
    __shared__ float rbf_s[N_RBF];
    __shared__ float u_s[3];
    __shared__ float fcut_s;
    int i = nbrs[2*e], j = nbrs[2*e+1];
    float d = dbuf[e];
    if (f < N_RBF) rbf_s[f] = sinf((f + 1) * PI_F * d / 5.0f) / d;
    if (f < 3)     u_s[f]   = unit[3*e + f];
    if (f == 0)    fcut_s   = (d < 5.0f) ? 0.5f * (cosf(PI_F * d / 5.0f) + 1.0f) : 0.0f;
    __syncthreads();

    float w0 = bd[f], w1 = bd[128 + f], w2 = bd[256 + f];
    #pragma unroll
    for (int r = 0; r < N_RBF; r++) {
        float rb = rbf_s[r];
        w0 += rb * Wd[r*384 + f];
        w1 += rb * Wd[r*384 + 128 + f];
        w2 += rb * Wd[r*384 + 256 + f];
    }
    float fc = fcut_s;
    size_t pj = (size_t)j * 384;
    float inv0 = phi[pj + f]       * w0 * fc;
    float inv1 = phi[pj + 128 + f] * w1 * fc;
    float inv2 = phi[pj + 256 + f] * w2 * fc;

    atomicAdd(&s_out[(size_t)i * FEAT + f], inv1);
    #pragma unroll
    for (int dd = 0; dd < 3; dd++) {
        float dv = u_s[dd] * inv2 + inv0 * v_in[((size_t)j*3 + dd) * FEAT + f];
        atomicAdd(&v_out[((size_t)i*3 + dd) * FEAT + f], dv);
    }
}

// ---------------- vnorm + concat ----------------
__global__ void k_vnorm_cat(const float* __restrict__ sb, const float* __restrict__ vv,
                            float* __restrict__ cat){
    int t = blockIdx.x * blockDim.x + threadIdx.x;
    if (t >= N_ATOMS * FEAT) return;
    int n = t >> 7, g = t & 127;
    float a = vv[((size_t)n*3 + 0) * FEAT + g];
    float b = vv[((size_t)n*3 + 1) * FEAT + g];
    float c = vv[((size_t)n*3 + 2) * FEAT + g];
    float nr = sqrtf(a*a + b*b + c*c + 1e-12f);
    cat[(size_t)n * 256 + g]        = sb[t];
    cat[(size_t)n * 256 + 128 + g]  = nr;
}

// ---------------- gated update ----------------
__global__ void k_update(const float* __restrict__ sb, const float* __restrict__ vb,
                         const float* __restrict__ uv, const float* __restrict__ vv,
                         const float* __restrict__ split,
                         float* __restrict__ sa, float* __restrict__ va){
    int t = blockIdx.x * blockDim.x + threadIdx.x;
    if (t >= N_ATOMS * FEAT) return;
    int n = t >> 7, g = t & 127;
    float avv = split[(size_t)n*384 + g];
    float asv = split[(size_t)n*384 + 128 + g];
    float ass = split[(size_t)n*384 + 256 + g];
    float dot = 0.f;
    #pragma unroll
    for (int d = 0; d < 3; d++) {
        size_t idx = ((size_t)n*3 + d) * FEAT + g;
        float u = uv[idx], w = vv[idx];
        dot += u * w;
        va[idx] = vb[idx] + u * avv;
    }
    sa[t] = sb[t] + dot * asv + ass;
}

// ---------------- host ----------------
static inline void gemm(const float* A, const float* B, const float* bias, float* C,
                        int M, int K, int N, int act, hipStream_t s){
    dim3 g((N + 15) / 16, (M + 15) / 16), b(16, 16);
    k_gemm<<<g, b, 0, s>>>(A, B, bias, C, M, K, N, act);
}

extern "C" void kernel_launch(void* const* d_in, const int* in_sizes, int n_in,
                              void* d_out, int out_size, void* d_ws, size_t ws_size,
                              hipStream_t stream) {
    float* ws  = (float*)d_ws;
    int* flag  = (int*)d_ws;       // ws[0]
    const int* z    = (const int*)d_in[1];
    const int* nbrs = (const int*)d_in[2];

    k_detect<<<1, 64, 0, stream>>>((const unsigned int*)d_in[0], flag);

    struct Cvt { int idx; size_t off; int n; };
    const Cvt items[] = {
        {0,A_XYZ,60000},{3,A_EMBED,12800},{4,A_W1,3*128*128},{5,A_B1,3*128},
        {6,A_W2,3*128*384},{7,A_B2,3*384},{8,A_WD,3*20*384},{9,A_BD,3*384},
        {10,A_U,3*128*128},{11,A_V,3*128*128},{12,A_WS1,3*256*128},{13,A_BS1,3*128},
        {14,A_WS2,3*128*384},{15,A_BS2,3*384},{16,A_WR1,128*128},{17,A_BR1,128},
        {18,A_WR2,128*64},{19,A_BR2,64},{20,A_WF1,64*128},{21,A_BF1,128},
        {22,A_WF2,128*128},{23,A_BF2,128},{24,A_WF3,128*5},{25,A_BF3,5}
    };
    for (const Cvt& it : items) {
        k_cvt<<<(it.n + 255) / 256, 256, 0, stream>>>(d_in[it.idx], ws + it.off, it.n, flag);
    }

    k_geom<<<(N_EDGES + 255) / 256, 256, 0, stream>>>(ws + A_XYZ, nbrs, ws + A_D, ws + A_UNIT);
    k_init_s<<<(N_ATOMS * FEAT + 255) / 256, 256, 0, stream>>>(ws + A_EMBED, z, ws + A_SA);
    k_zero<<<(N_ATOMS * 3 * FEAT + 255) / 256, 256, 0, stream>>>(ws + A_VA, N_ATOMS * 3 * FEAT);

    for (int l = 0; l < N_CONV; l++) {
        const float* W1l  = ws + A_W1  + (size_t)l * 128 * 128;
        const float* b1l  = ws + A_B1  + (size_t)l * 128;
        const float* W2l  = ws + A_W2  + (size_t)l * 128 * 384;
        const float* b2l  = ws + A_B2  + (size_t)l * 384;
        const float* Wdl  = ws + A_WD  + (size_t)l * 20 * 384;
        const float* bdl  = ws + A_BD  + (size_t)l * 384;
        const float* Ul   = ws + A_U   + (size_t)l * 128 * 128;
        const float* Vl   = ws + A_V   + (size_t)l * 128 * 128;
        const float* Ws1l = ws + A_WS1 + (size_t)l * 256 * 128;
        const float* bs1l = ws + A_BS1 + (size_t)l * 128;
        const float* Ws2l = ws + A_WS2 + (size_t)l * 128 * 384;
        const float* bs2l = ws + A_BS2 + (size_t)l * 384;

        // phi = dense(silu(dense(s, W1, b1)), W2, b2)
        gemm(ws + A_SA,   W1l, b1l, ws + A_PHIH, N_ATOMS, 128, 128, 1, stream);
        gemm(ws + A_PHIH, W2l, b2l, ws + A_PHI,  N_ATOMS, 128, 384, 0, stream);

        // s_b = s_a ; v_b = v_a (scatter baselines)
        k_copy<<<(N_ATOMS*FEAT + 255)/256, 256, 0, stream>>>(ws + A_SB, ws + A_SA, N_ATOMS*FEAT);
        k_copy<<<(N_ATOMS*3*FEAT + 255)/256, 256, 0, stream>>>(ws + A_VB, ws + A_VA, N_ATOMS*3*FEAT);

        // edge messages + scatter into s_b, v_b
        k_edge<<<N_EDGES, 128, 0, stream>>>(ws + A_PHI, ws + A_VA, ws + A_UNIT, ws + A_D,
                                            nbrs, Wdl, bdl, ws + A_SB, ws + A_VB);

        // u_v, v_v (v stored (n,3,f) -> flat 60000x128 GEMMs, no bias)
        gemm(ws + A_VB, Ul, nullptr, ws + A_PHI, N_ATOMS*3, 128, 128, 0, stream); // uv (aliases phi)
        gemm(ws + A_VB, Vl, nullptr, ws + A_VV,  N_ATOMS*3, 128, 128, 0, stream); // vv

        // cat = [s_b, ||v_v||]
        k_vnorm_cat<<<(N_ATOMS*FEAT + 255)/256, 256, 0, stream>>>(ws + A_SB, ws + A_VV, ws + A_CAT);

        // split = dense(silu(dense(cat, Ws1, bs1)), Ws2, bs2)
        gemm(ws + A_CAT,  Ws1l, bs1l, ws + A_PHIH,  N_ATOMS, 256, 128, 1, stream);
        gemm(ws + A_PHIH, Ws2l, bs2l, ws + A_SPLIT, N_ATOMS, 128, 384, 0, stream);

        // gated update -> s_a, v_a
        k_update<<<(N_ATOMS*FEAT + 255)/256, 256, 0, stream>>>(
            ws + A_SB, ws + A_VB, ws + A_PHI, ws + A_VV, ws + A_SPLIT, ws + A_SA, ws + A_VA);
    }

    // readout
    gemm(ws + A_SA,   ws + A_WR1, ws + A_BR1, ws + A_PHIH, N_ATOMS, 128, 128, 1, stream); // t1
    gemm(ws + A_PHIH, ws + A_WR2, ws + A_BR2, ws + A_CAT,  N_ATOMS, 128, 64,  0, stream); // atom_fea
    gemm(ws + A_CAT,  ws + A_WF1, ws + A_BF1, ws + A_PHI,  N_ATOMS, 64,  128, 1, stream); // h
    gemm(ws + A_PHI,  ws + A_WF2, ws + A_BF2, ws + A_PHIH, N_ATOMS, 128, 128, 1, stream); // h2
    gemm(ws + A_PHIH, ws + A_WF3, ws + A_BF3, ws + A_OUTF, N_ATOMS, 128, N_OUT_, 0, stream);

    k_store_out<<<(N_ATOMS*N_OUT_ + 255)/256, 256, 0, stream>>>(ws + A_OUTF, d_out,
                                                                N_ATOMS*N_OUT_, flag);
}

// Round 3
// 1729.502 us; speedup vs baseline: 2.3871x; 2.3871x over previous
//
#include <hip/hip_runtime.h>
#include <hip/hip_bf16.h>
#include <math.h>

#define N_ATOMS 20000
#define N_EDGES 320000
#define FEAT 128
#define N_RBF 20
#define N_CONV 3
#define N_OUT_ 5
#define PI_F 3.14159265358979f
#define M20P 20032
#define M60P 60032

typedef unsigned short ushort;
typedef __bf16 bf16x8 __attribute__((ext_vector_type(8)));
typedef float f32x4 __attribute__((ext_vector_type(4)));

__device__ __forceinline__ float b2f(ushort u){ return __uint_as_float(((unsigned)u) << 16); }
__device__ __forceinline__ ushort f2b(float x){
    unsigned u = __float_as_uint(x);
    return (ushort)((u + 0x7FFFu + ((u >> 16) & 1u)) >> 16);   // RNE
}

// ---------------- workspace layout (float slots) ----------------
constexpr size_t rnd64(size_t x){ return (x + 63) & ~size_t(63); }
constexpr size_t F_XYZ  = 64;                                  // flag at ws[0]
constexpr size_t F_EMB  = rnd64(F_XYZ + 60000);
constexpr size_t F_B1   = rnd64(F_EMB + 12800);
constexpr size_t F_B2   = rnd64(F_B1  + 3*128);
constexpr size_t F_WD   = rnd64(F_B2  + 3*384);
constexpr size_t F_BD   = rnd64(F_WD  + 3*20*384);
constexpr size_t F_BS1  = rnd64(F_BD  + 3*384);
constexpr size_t F_BS2  = rnd64(F_BS1 + 3*128);
constexpr size_t F_BR1  = rnd64(F_BS2 + 3*384);
constexpr size_t F_BR2  = rnd64(F_BR1 + 128);
constexpr size_t F_BF1  = rnd64(F_BR2 + 64);
constexpr size_t F_BF2  = rnd64(F_BF1 + 128);
constexpr size_t F_BF3  = rnd64(F_BF2 + 128);
constexpr size_t F_FC   = rnd64(F_BF3 + 8);
constexpr size_t F_UNIT = rnd64(F_FC   + N_EDGES);
constexpr size_t F_G    = rnd64(F_UNIT + 3*N_EDGES);
constexpr size_t F_CNT  = rnd64(F_G    + (size_t)N_EDGES*N_RBF);
constexpr size_t F_ROW  = rnd64(F_CNT  + N_ATOMS);
constexpr size_t F_CUR  = rnd64(F_ROW  + N_ATOMS + 1);
constexpr size_t F_EID  = rnd64(F_CUR  + N_ATOMS);
constexpr size_t F_S    = rnd64(F_EID  + N_EDGES);
constexpr size_t F_V    = rnd64(F_S    + (size_t)N_ATOMS*FEAT);
constexpr size_t F_PHI  = rnd64(F_V    + (size_t)60000*FEAT);     // phi f32, later uv f32
constexpr size_t F_VV   = rnd64(F_PHI  + (size_t)N_ATOMS*384);
constexpr size_t F_SPL  = rnd64(F_VV   + (size_t)60000*FEAT);     // split f32; CAT hi/lo pair aliases here
constexpr size_t F_OUT  = rnd64(F_SPL  + (size_t)N_ATOMS*384);
// bf16 hi/lo pair buffers (slot counts = elems/2)
constexpr size_t H_SHI  = rnd64(F_OUT  + N_ATOMS*N_OUT_);
constexpr size_t H_SLO  = rnd64(H_SHI  + (size_t)M20P*128/2);
constexpr size_t H_VHI  = rnd64(H_SLO  + (size_t)M20P*128/2);
constexpr size_t H_VLO  = rnd64(H_VHI  + (size_t)M60P*128/2);
constexpr size_t H_HAHI = rnd64(H_VLO  + (size_t)M60P*128/2);
constexpr size_t H_HALO = rnd64(H_HAHI + (size_t)M20P*128/2);
constexpr size_t H_HBHI = rnd64(H_HALO + (size_t)M20P*128/2);
constexpr size_t H_HBLO = rnd64(H_HBHI + (size_t)M20P*128/2);
constexpr size_t H_AFHI = rnd64(H_HBLO + (size_t)M20P*128/2);
constexpr size_t H_AFLO = rnd64(H_AFHI + (size_t)M20P*64/2);
constexpr size_t H_WT   = rnd64(H_AFLO + (size_t)M20P*64/2);
// weight offsets (in ushort elems, within hi or lo half)
constexpr size_t O_W1T=0, O_W2T=49152, O_UT=196608, O_VT=245760, O_WS1T=294912,
                 O_WS2T=393216, O_WR1T=540672, O_WR2T=557056, O_WF1T=565248,
                 O_WF2T=573440, O_WF3T=589824, O_WTOT=598016;

// ---------------- dtype detection ----------------
__global__ void k_detect(const unsigned int* __restrict__ bits, int* flag){
    __shared__ int cnt;
    if (threadIdx.x == 0) cnt = 0;
    __syncthreads();
    unsigned int lo = bits[threadIdx.x] & 0xFFFFu;
    if (lo >= 0x3000u && lo <= 0x4100u) atomicAdd(&cnt, 1);
    __syncthreads();
    if (threadIdx.x == 0) *flag = (cnt >= 48) ? 1 : 0;
}

__global__ void k_cvt(const void* __restrict__ src, float* __restrict__ dst, int n,
                      const int* __restrict__ flag){
    int t = blockIdx.x * blockDim.x + threadIdx.x;
    if (t >= n) return;
    if (*flag) dst[t] = b2f(((const ushort*)src)[t]);
    else       dst[t] = ((const float*)src)[t];
}

// weight K x N (+src elem offset) -> bf16 hi/lo transposed Npad x K, zero pad
__global__ void k_wt2(const void* __restrict__ src, int src_off,
                      ushort* __restrict__ dhi, ushort* __restrict__ dlo,
                      int K, int N, int Npad, const int* __restrict__ flag){
    int t = blockIdx.x * blockDim.x + threadIdx.x;
    if (t >= Npad * K) return;
    int n = t / K, k = t - n * K;
    if (n >= N) { dhi[t] = 0; dlo[t] = 0; return; }
    float w;
    if (*flag) w = b2f(((const ushort*)src)[src_off + k * N + n]);
    else       w = ((const float*)src)[src_off + k * N + n];
    ushort hi = f2b(w);
    dhi[t] = hi;
    dlo[t] = f2b(w - b2f(hi));
}

__global__ void k_store_out(const float* __restrict__ src, void* __restrict__ dst, int n,
                            const int* __restrict__ flag){
    int t = blockIdx.x * blockDim.x + threadIdx.x;
    if (t >= n) return;
    float v = src[t];
    if (*flag) ((ushort*)dst)[t] = f2b(v);
    else       ((float*)dst)[t] = v;
}

// ---------------- utility ----------------
__global__ void k_zero_f(float* p, int n){
    int t = blockIdx.x * blockDim.x + threadIdx.x;
    if (t < n) p[t] = 0.f;
}
__global__ void k_zero_i(int* p, int n){
    int t = blockIdx.x * blockDim.x + threadIdx.x;
    if (t < n) p[t] = 0;
}
__global__ void k_init_s(const float* __restrict__ embed, const int* __restrict__ z,
                         float* __restrict__ s, ushort* __restrict__ shi,
                         ushort* __restrict__ slo){
    int t = blockIdx.x * blockDim.x + threadIdx.x;
    if (t >= N_ATOMS * FEAT) return;
    int n = t >> 7, f = t & 127;
    float v = embed[z[n] * FEAT + f];
    s[t] = v;
    ushort h = f2b(v); shi[t] = h; slo[t] = f2b(v - b2f(h));
}

// ---------------- geometry ----------------
__global__ void k_geom(const float* __restrict__ xyz, const int* __restrict__ nbrs,
                       float* __restrict__ fcb, float* __restrict__ unit,
                       float* __restrict__ G){
    int e = blockIdx.x * blockDim.x + threadIdx.x;
    if (e >= N_EDGES) return;
    int i = nbrs[2*e], j = nbrs[2*e+1];
    float rx = xyz[3*j]   - xyz[3*i];
    float ry = xyz[3*j+1] - xyz[3*i+1];
    float rz = xyz[3*j+2] - xyz[3*i+2];
    float d  = sqrtf(rx*rx + ry*ry + rz*rz + 1e-12f);
    float inv = 1.0f / d;
    unit[3*e] = rx*inv; unit[3*e+1] = ry*inv; unit[3*e+2] = rz*inv;
    float fc = (d < 5.0f) ? 0.5f * (cosf(PI_F * d * 0.2f) + 1.0f) : 0.0f;
    fcb[e] = fc;
    float base = PI_F * d * 0.2f;
    #pragma unroll
    for (int r = 0; r < N_RBF; r++)
        G[(size_t)e*N_RBF + r] = sinf((r+1) * base) * inv * fc;
}

// ---------------- CSR build ----------------
__global__ void k_hist(const int* __restrict__ nbrs, int* __restrict__ cnt){
    int e = blockIdx.x * blockDim.x + threadIdx.x;
    if (e < N_EDGES) atomicAdd(&cnt[nbrs[2*e]], 1);
}
__global__ void k_scan(const int* __restrict__ cnt, int* __restrict__ row, int* __restrict__ cur){
    __shared__ int ls[256];
    int t = threadIdx.x, base = t * 80;
    int s = 0;
    for (int k = 0; k < 80; k++){ int i = base + k; if (i < N_ATOMS) s += cnt[i]; }
    ls[t] = s; __syncthreads();
    for (int off = 1; off < 256; off <<= 1){
        int v = (t >= off) ? ls[t - off] : 0;
        __syncthreads();
        ls[t] += v;
        __syncthreads();
    }
    int run = ls[t] - s;
    for (int k = 0; k < 80; k++){
        int i = base + k;
        if (i < N_ATOMS){ row[i] = run; cur[i] = run; run += cnt[i]; }
    }
    if (t == 255) row[N_ATOMS] = ls[255];
}
__global__ void k_fill(const int* __restrict__ nbrs, int* __restrict__ cur, int* __restrict__ eid){
    int e = blockIdx.x * blockDim.x + threadIdx.x;
    if (e >= N_EDGES) return;
    int p = atomicAdd(&cur[nbrs[2*e]], 1);
    eid[p] = e;
}

// ---------------- split-bf16 MFMA GEMM ----------------
// C = act(A @ Bt^T + bias), A = Ahi+Alo (MxK bf16 pairs), Bt = Bthi+Btlo (NpadxK)
// computed as Ahi@Bhi + Ahi@Blo + Alo@Bhi  (~f32 precision)
__global__ __launch_bounds__(256) void k_gemm3(
    const ushort* __restrict__ Ahi, const ushort* __restrict__ Alo,
    const ushort* __restrict__ Bthi, const ushort* __restrict__ Btlo,
    const float* __restrict__ bias, int M, int K, int N, int act,
    float* __restrict__ Cf, ushort* __restrict__ Chi, ushort* __restrict__ Clo)
{
    int wave = threadIdx.x >> 6, lane = threadIdx.x & 63;
    int l15 = lane & 15, quad = lane >> 4;
    int m0 = blockIdx.y * 64 + wave * 16;
    int n0 = blockIdx.x * 64;
    const ushort* aph = Ahi  + (size_t)(m0 + l15) * K + quad * 8;
    const ushort* apl = Alo  + (size_t)(m0 + l15) * K + quad * 8;
    const ushort* bph = Bthi + (size_t)(n0 + l15) * K + quad * 8;
    const ushort* bpl = Btlo + (size_t)(n0 + l15) * K + quad * 8;
    f32x4 acc[4];
    #pragma unroll
    for (int c = 0; c < 4; c++) acc[c] = (f32x4){0.f, 0.f, 0.f, 0.f};
    for (int k0 = 0; k0 < K; k0 += 32) {
        bf16x8 ah = *reinterpret_cast<const bf16x8*>(aph + k0);
        bf16x8 al = *reinterpret_cast<const bf16x8*>(apl + k0);
        #pragma unroll
        for (int c = 0; c < 4; c++) {
            bf16x8 bh = *reinterpret_cast<const bf16x8*>(bph + (size_t)c * 16 * K + k0);
            bf16x8 bl = *reinterpret_cast<const bf16x8*>(bpl + (size_t)c * 16 * K + k0);
            acc[c] = __builtin_amdgcn_mfma_f32_16x16x32_bf16(al, bh, acc[c], 0, 0, 0);
            acc[c] = __builtin_amdgcn_mfma_f32_16x16x32_bf16(ah, bl, acc[c], 0, 0, 0);
            acc[c] = __builtin_amdgcn_mfma_f32_16x16x32_bf16(ah, bh, acc[c], 0, 0, 0);
        }
    }
    int row_base = m0 + quad * 4;
    #pragma unroll
    for (int c = 0; c < 4; c++) {
        int col = n0 + c * 16 + l15;
        #pragma unroll
        for (int r = 0; r < 4; r++) {
            int row = row_base + r;
            if (row < M && col < N) {
                float v = acc[c][r];
                if (bias) v += bias[col];
                if (act)  v = v / (1.f + expf(-v));
                size_t idx = (size_t)row * N + col;
                if (Cf)  Cf[idx] = v;
                if (Chi) { ushort h = f2b(v); Chi[idx] = h; Clo[idx] = f2b(v - b2f(h)); }
            }
        }
    }
}

// ---------------- edge gather-reduce (f32, no atomics) ----------------
// block = atom i, thread = channel f. Reads phi (f32), V (f32, untouched).
// Writes s[i] (in place, own row) and hi/lo pair of post-message v.
__global__ __launch_bounds__(128) void k_edge3(
    const float* __restrict__ phi, const float* __restrict__ vin,
    const float* __restrict__ unit, const float* __restrict__ fcb,
    const float* __restrict__ G,
    const int* __restrict__ nbrs, const int* __restrict__ row, const int* __restrict__ eid,
    const float* __restrict__ Wd, const float* __restrict__ bd,
    float* __restrict__ s, ushort* __restrict__ vhi, ushort* __restrict__ vlo)
{
    int i = blockIdx.x, f = threadIdx.x;
    float wdr[3 * N_RBF];
    #pragma unroll
    for (int r = 0; r < N_RBF; r++) {
        wdr[r]           = Wd[r*384 + f];
        wdr[N_RBF + r]   = Wd[r*384 + 128 + f];
        wdr[2*N_RBF + r] = Wd[r*384 + 256 + f];
    }
    float bd0 = bd[f], bd1 = bd[128 + f], bd2 = bd[256 + f];
    float sacc = 0.f, va0 = 0.f, va1 = 0.f, va2 = 0.f;
    int beg = row[i], end = row[i + 1];
    for (int idx = beg; idx < end; idx++) {
        int e = eid[idx];
        int j = nbrs[2*e + 1];
        float fc = fcb[e];
        float w0 = bd0 * fc, w1 = bd1 * fc, w2 = bd2 * fc;
        const float* g = G + (size_t)e * N_RBF;
        #pragma unroll
        for (int r = 0; r < N_RBF; r++) {
            float gr = g[r];
            w0 = fmaf(gr, wdr[r],           w0);
            w1 = fmaf(gr, wdr[N_RBF + r],   w1);
            w2 = fmaf(gr, wdr[2*N_RBF + r], w2);
        }
        size_t pj = (size_t)j * 384;
        float inv0 = phi[pj + f]       * w0;
        float inv1 = phi[pj + 128 + f] * w1;
        float inv2 = phi[pj + 256 + f] * w2;
        float ux = unit[3*e], uy = unit[3*e+1], uz = unit[3*e+2];
        size_t vj = (size_t)j * 384 + f;
        sacc += inv1;
        va0 = fmaf(inv0, vin[vj],       fmaf(ux, inv2, va0));
        va1 = fmaf(inv0, vin[vj + 128], fmaf(uy, inv2, va1));
        va2 = fmaf(inv0, vin[vj + 256], fmaf(uz, inv2, va2));
    }
    s[(size_t)i * FEAT + f] += sacc;
    size_t vi = (size_t)i * 384 + f;
    float n0 = vin[vi] + va0, n1 = vin[vi + 128] + va1, n2 = vin[vi + 256] + va2;
    ushort h;
    h = f2b(n0); vhi[vi]       = h; vlo[vi]       = f2b(n0 - b2f(h));
    h = f2b(n1); vhi[vi + 128] = h; vlo[vi + 128] = f2b(n1 - b2f(h));
    h = f2b(n2); vhi[vi + 256] = h; vlo[vi + 256] = f2b(n2 - b2f(h));
}

// ---------------- vnorm + concat -> CAT hi/lo ----------------
__global__ void k_vnorm_cat(const float* __restrict__ s, const float* __restrict__ vv,
                            ushort* __restrict__ chi, ushort* __restrict__ clo){
    int t = blockIdx.x * blockDim.x + threadIdx.x;
    if (t >= N_ATOMS * FEAT) return;
    int n = t >> 7, g = t & 127;
    size_t b = (size_t)n * 384 + g;
    float a0 = vv[b], a1 = vv[b + 128], a2 = vv[b + 256];
    float nr = sqrtf(a0*a0 + a1*a1 + a2*a2 + 1e-12f);
    float sv = s[t];
    size_t c0 = (size_t)n * 256 + g;
    ushort h;
    h = f2b(sv); chi[c0]       = h; clo[c0]       = f2b(sv - b2f(h));
    h = f2b(nr); chi[c0 + 128] = h; clo[c0 + 128] = f2b(nr - b2f(h));
}

// ---------------- gated update ----------------
__global__ void k_update(const float* __restrict__ uv, const float* __restrict__ vv,
                         const float* __restrict__ spl,
                         const ushort* __restrict__ vhi, const ushort* __restrict__ vlo,
                         float* __restrict__ s, float* __restrict__ v,
                         ushort* __restrict__ shi, ushort* __restrict__ slo){
    int t = blockIdx.x * blockDim.x + threadIdx.x;
    if (t >= N_ATOMS * FEAT) return;
    int n = t >> 7, g = t & 127;
    size_t sp = (size_t)n * 384 + g;
    float avv = spl[sp], asv = spl[sp + 128], ass = spl[sp + 256];
    float dot = 0.f;
    size_t b = (size_t)n * 384 + g;
    #pragma unroll
    for (int d = 0; d < 3; d++) {
        size_t idx = b + (size_t)d * 128;
        float u  = uv[idx];
        float w  = vv[idx];
        float vb = b2f(vhi[idx]) + b2f(vlo[idx]);
        dot = fmaf(u, w, dot);
        v[idx] = vb + u * avv;
    }
    float ns = s[t] + dot * asv + ass;
    s[t] = ns;
    ushort h = f2b(ns); shi[t] = h; slo[t] = f2b(ns - b2f(h));
}

// ---------------- host ----------------
struct Pair { ushort* hi; ushort* lo; };

static inline void gemm3(Pair A, Pair B, const float* bias,
                         int M, int K, int N, int Npad, int act,
                         float* Cf, Pair C, hipStream_t s){
    dim3 g(Npad / 64, (M + 63) / 64), b(256);
    k_gemm3<<<g, b, 0, s>>>(A.hi, A.lo, B.hi, B.lo, bias, M, K, N, act, Cf, C.hi, C.lo);
}

extern "C" void kernel_launch(void* const* d_in, const int* in_sizes, int n_in,
                              void* d_out, int out_size, void* d_ws, size_t ws_size,
                              hipStream_t stream) {
    float* ws = (float*)d_ws;
    int* flag = (int*)d_ws;
    const int* z    = (const int*)d_in[1];
    const int* nbrs = (const int*)d_in[2];

    k_detect<<<1, 64, 0, stream>>>((const unsigned int*)d_in[0], flag);

    struct Cvt { int idx; size_t off; int n; };
    const Cvt items[] = {
        {0,F_XYZ,60000},{3,F_EMB,12800},{5,F_B1,3*128},{7,F_B2,3*384},
        {8,F_WD,3*20*384},{9,F_BD,3*384},{13,F_BS1,3*128},{15,F_BS2,3*384},
        {17,F_BR1,128},{19,F_BR2,64},{21,F_BF1,128},{23,F_BF2,128},{25,F_BF3,5}
    };
    for (const Cvt& it : items)
        k_cvt<<<(it.n + 255)/256, 256, 0, stream>>>(d_in[it.idx], ws + it.off, it.n, flag);

    ushort* wb = (ushort*)(ws + H_WT);
    auto WP = [&](size_t off){ return Pair{ wb + off, wb + O_WTOT + off }; };
    auto wt = [&](int idx, int src_off, size_t off, int K, int N, int Npad){
        int n = Npad * K;
        k_wt2<<<(n + 255)/256, 256, 0, stream>>>(d_in[idx], src_off,
                                                 wb + off, wb + O_WTOT + off, K, N, Npad, flag);
    };
    for (int l = 0; l < 3; l++) {
        wt(4,  l*16384, O_W1T  + l*16384, 128, 128, 128);
        wt(6,  l*49152, O_W2T  + l*49152, 128, 384, 384);
        wt(10, l*16384, O_UT   + l*16384, 128, 128, 128);
        wt(11, l*16384, O_VT   + l*16384, 128, 128, 128);
        wt(12, l*32768, O_WS1T + l*32768, 256, 128, 128);
        wt(14, l*49152, O_WS2T + l*49152, 128, 384, 384);
    }
    wt(16, 0, O_WR1T, 128, 128, 128);
    wt(18, 0, O_WR2T, 128,  64,  64);
    wt(20, 0, O_WF1T,  64, 128, 128);
    wt(22, 0, O_WF2T, 128, 128, 128);
    wt(24, 0, O_WF3T, 128,   5,  64);

    // geometry + CSR
    k_geom<<<(N_EDGES+255)/256, 256, 0, stream>>>(ws + F_XYZ, nbrs, ws + F_FC, ws + F_UNIT, ws + F_G);
    int* cnt = (int*)(ws + F_CNT); int* row = (int*)(ws + F_ROW);
    int* cur = (int*)(ws + F_CUR); int* eid = (int*)(ws + F_EID);
    k_zero_i<<<(N_ATOMS+255)/256, 256, 0, stream>>>(cnt, N_ATOMS);
    k_hist<<<(N_EDGES+255)/256, 256, 0, stream>>>(nbrs, cnt);
    k_scan<<<1, 256, 0, stream>>>(cnt, row, cur);
    k_fill<<<(N_EDGES+255)/256, 256, 0, stream>>>(nbrs, cur, eid);

    float* S   = ws + F_S;
    float* V   = ws + F_V;
    float* PHI = ws + F_PHI;       // phi f32, then uv f32
    float* VV  = ws + F_VV;
    float* SPL = ws + F_SPL;
    Pair SHL { (ushort*)(ws + H_SHI),  (ushort*)(ws + H_SLO)  };
    Pair VHL { (ushort*)(ws + H_VHI),  (ushort*)(ws + H_VLO)  };
    Pair HA  { (ushort*)(ws + H_HAHI), (ushort*)(ws + H_HALO) };
    Pair HB  { (ushort*)(ws + H_HBHI), (ushort*)(ws + H_HBLO) };
    Pair AF  { (ushort*)(ws + H_AFHI), (ushort*)(ws + H_AFLO) };
    Pair CAT { (ushort*)(ws + F_SPL),  (ushort*)(ws + F_SPL) + (size_t)M20P*256 };
    Pair NOP { nullptr, nullptr };

    k_init_s<<<(N_ATOMS*FEAT+255)/256, 256, 0, stream>>>(ws + F_EMB, z, S, SHL.hi, SHL.lo);
    k_zero_f<<<(60000*FEAT+255)/256, 256, 0, stream>>>(V, 60000*FEAT);

    for (int l = 0; l < N_CONV; l++) {
        // phi = dense(silu(dense(s)))
        gemm3(SHL, WP(O_W1T + l*16384), ws + F_B1 + l*128, N_ATOMS, 128, 128, 128, 1, nullptr, HA, stream);
        gemm3(HA,  WP(O_W2T + l*49152), ws + F_B2 + l*384, N_ATOMS, 128, 384, 384, 0, PHI, NOP, stream);
        // edge gather-reduce: s += msgs (in place), emit hi/lo of post-message v
        k_edge3<<<N_ATOMS, 128, 0, stream>>>(PHI, V, ws + F_UNIT, ws + F_FC, ws + F_G,
                                             nbrs, row, eid,
                                             ws + F_WD + (size_t)l*20*384, ws + F_BD + l*384,
                                             S, VHL.hi, VHL.lo);
        // uv (into PHI buffer), vv
        gemm3(VHL, WP(O_UT + l*16384), nullptr, 60000, 128, 128, 128, 0, PHI, NOP, stream);
        gemm3(VHL, WP(O_VT + l*16384), nullptr, 60000, 128, 128, 128, 0, VV,  NOP, stream);
        // cat = [s, ||vv||] hi/lo (aliases SPL region; SPL written after CAT consumed)
        k_vnorm_cat<<<(N_ATOMS*FEAT+255)/256, 256, 0, stream>>>(S, VV, CAT.hi, CAT.lo);
        // split = dense(silu(dense(cat)))
        gemm3(CAT, WP(O_WS1T + l*32768), ws + F_BS1 + l*128, N_ATOMS, 256, 128, 128, 1, nullptr, HB, stream);
        gemm3(HB,  WP(O_WS2T + l*49152), ws + F_BS2 + l*384, N_ATOMS, 128, 384, 384, 0, SPL, NOP, stream);
        // gated update -> S, V (f32) + s hi/lo
        k_update<<<(N_ATOMS*FEAT+255)/256, 256, 0, stream>>>(PHI, VV, SPL, VHL.hi, VHL.lo,
                                                             S, V, SHL.hi, SHL.lo);
    }

    // readout
    gemm3(SHL, WP(O_WR1T), ws + F_BR1, N_ATOMS, 128, 128, 128, 1, nullptr, HA, stream);
    gemm3(HA,  WP(O_WR2T), ws + F_BR2, N_ATOMS, 128,  64,  64, 0, nullptr, AF, stream);
    gemm3(AF,  WP(O_WF1T), ws + F_BF1, N_ATOMS,  64, 128, 128, 1, nullptr, HB, stream);
    gemm3(HB,  WP(O_WF2T), ws + F_BF2, N_ATOMS, 128, 128, 128, 1, nullptr, HA, stream);
    gemm3(HA,  WP(O_WF3T), ws + F_BF3, N_ATOMS, 128, N_OUT_, 64, 0, ws + F_OUT, NOP, stream);

    k_store_out<<<(N_ATOMS*N_OUT_+255)/256, 256, 0, stream>>>(ws + F_OUT, d_out, N_ATOMS*N_OUT_, flag);
}

// Round 4
// 1629.077 us; speedup vs baseline: 2.5343x; 1.0616x over previous
//
#include <hip/hip_runtime.h>
#include <hip/hip_bf16.h>
#include <math.h>

#define N_ATOMS 20000
#define N_EDGES 320000
#define FEAT 128
#define N_RBF 20
#define N_CONV 3
#define N_OUT_ 5
#define PI_F 3.14159265358979f
#define M20P 20032
#define M60P 60032

typedef unsigned short ushort;
typedef __bf16 bf16x8 __attribute__((ext_vector_type(8)));
typedef float f32x4 __attribute__((ext_vector_type(4)));

__device__ __forceinline__ float b2f(ushort u){ return __uint_as_float(((unsigned)u) << 16); }
__device__ __forceinline__ ushort f2b(float x){
    unsigned u = __float_as_uint(x);
    return (ushort)((u + 0x7FFFu + ((u >> 16) & 1u)) >> 16);   // RNE
}

// ---------------- workspace layout (float slots) ----------------
constexpr size_t rnd64(size_t x){ return (x + 63) & ~size_t(63); }
constexpr size_t F_XYZ  = 64;                                  // flag at ws[0]
constexpr size_t F_EMB  = rnd64(F_XYZ + 60000);
constexpr size_t F_B1   = rnd64(F_EMB + 12800);
constexpr size_t F_B2   = rnd64(F_B1  + 3*128);
constexpr size_t F_WD   = rnd64(F_B2  + 3*384);
constexpr size_t F_BD   = rnd64(F_WD  + 3*20*384);
constexpr size_t F_BS1  = rnd64(F_BD  + 3*384);
constexpr size_t F_BS2  = rnd64(F_BS1 + 3*128);
constexpr size_t F_BR1  = rnd64(F_BS2 + 3*384);
constexpr size_t F_BR2  = rnd64(F_BR1 + 128);
constexpr size_t F_BF1  = rnd64(F_BR2 + 64);
constexpr size_t F_BF2  = rnd64(F_BF1 + 128);
constexpr size_t F_BF3  = rnd64(F_BF2 + 128);
constexpr size_t F_FC   = rnd64(F_BF3 + 8);
constexpr size_t F_UNIT = rnd64(F_FC   + N_EDGES);
constexpr size_t F_G    = rnd64(F_UNIT + 3*N_EDGES);
constexpr size_t F_CNT  = rnd64(F_G    + (size_t)N_EDGES*N_RBF);
constexpr size_t F_ROW  = rnd64(F_CNT  + N_ATOMS);
constexpr size_t F_CUR  = rnd64(F_ROW  + N_ATOMS + 1);
constexpr size_t F_EID  = rnd64(F_CUR  + N_ATOMS);
constexpr size_t F_S    = rnd64(F_EID  + N_EDGES);
constexpr size_t F_V    = rnd64(F_S    + (size_t)N_ATOMS*FEAT);
constexpr size_t F_PHI  = rnd64(F_V    + (size_t)60000*FEAT);     // phi f32, later uv f32
constexpr size_t F_VV   = rnd64(F_PHI  + (size_t)N_ATOMS*384);
constexpr size_t F_SPL  = rnd64(F_VV   + (size_t)60000*FEAT);     // split f32; CAT hi/lo aliases
constexpr size_t F_OUT  = rnd64(F_SPL  + (size_t)N_ATOMS*384);
// bf16 hi/lo pair buffers (slot counts = elems/2)
constexpr size_t H_SHI  = rnd64(F_OUT  + N_ATOMS*N_OUT_);
constexpr size_t H_SLO  = rnd64(H_SHI  + (size_t)M20P*128/2);
constexpr size_t H_VHI  = rnd64(H_SLO  + (size_t)M20P*128/2);
constexpr size_t H_VLO  = rnd64(H_VHI  + (size_t)M60P*128/2);
constexpr size_t H_HAHI = rnd64(H_VLO  + (size_t)M60P*128/2);
constexpr size_t H_HALO = rnd64(H_HAHI + (size_t)M20P*128/2);
constexpr size_t H_HBHI = rnd64(H_HALO + (size_t)M20P*128/2);
constexpr size_t H_HBLO = rnd64(H_HBHI + (size_t)M20P*128/2);
constexpr size_t H_AFHI = rnd64(H_HBLO + (size_t)M20P*128/2);
constexpr size_t H_AFLO = rnd64(H_AFHI + (size_t)M20P*64/2);
constexpr size_t H_WT   = rnd64(H_AFLO + (size_t)M20P*64/2);
// weight offsets (ushort elems within hi half; lo = +O_WTOT)
constexpr size_t O_W1T=0, O_W2T=49152, O_UT=196608, O_VT=245760, O_WS1T=294912,
                 O_WS2T=393216, O_WR1T=540672, O_WR2T=557056, O_WF1T=565248,
                 O_WF2T=573440, O_WF3T=589824, O_WTOT=598016;

// ---------------- dtype detection ----------------
__global__ void k_detect(const unsigned int* __restrict__ bits, int* flag){
    __shared__ int cnt;
    if (threadIdx.x == 0) cnt = 0;
    __syncthreads();
    unsigned int lo = bits[threadIdx.x] & 0xFFFFu;
    if (lo >= 0x3000u && lo <= 0x4100u) atomicAdd(&cnt, 1);
    __syncthreads();
    if (threadIdx.x == 0) *flag = (cnt >= 48) ? 1 : 0;
}

// ---------------- mega f32-convert (13 segments, 1 launch) ----------------
struct P13 { const void* p[13]; };
__global__ void k_cvt_all(P13 sp, float* __restrict__ ws, const int* __restrict__ flag){
    constexpr int   NSEG = 13;
    constexpr int    SZ[NSEG] = {60000,12800,384,1152,23040,1152,384,1152,128,64,128,128,5};
    constexpr size_t DO_[NSEG]= {F_XYZ,F_EMB,F_B1,F_B2,F_WD,F_BD,F_BS1,F_BS2,F_BR1,F_BR2,F_BF1,F_BF2,F_BF3};
    int t = blockIdx.x * blockDim.x + threadIdx.x;
    int bf = *flag;
    #pragma unroll
    for (int s = 0; s < NSEG; s++){
        if (t < SZ[s]){
            float v = bf ? b2f(((const ushort*)sp.p[s])[t]) : ((const float*)sp.p[s])[t];
            ws[DO_[s] + t] = v;
            return;
        }
        t -= SZ[s];
    }
}

// ---------------- mega weight transpose hi/lo (23 segments, 1 launch) ----------------
// src K x N row-major -> dst Npad x K (transposed), zero-padded, hi+lo bf16
struct P11 { const void* p[11]; };
__global__ void k_wt_all(P11 sp, ushort* __restrict__ wb, const int* __restrict__ flag){
    constexpr int NSEG = 23;
    // per-layer x3: W1,W2,U,V,Ws1,Ws2 then WR1,WR2,WF1,WF2,WF3
    constexpr int SRC[NSEG]  = {0,1,2,3,4,5, 0,1,2,3,4,5, 0,1,2,3,4,5, 6,7,8,9,10};
    constexpr int SOFF[NSEG] = {0,0,0,0,0,0, 16384,49152,16384,16384,32768,49152,
                                32768,98304,32768,32768,65536,98304, 0,0,0,0,0};
    constexpr size_t DOFF[NSEG]={O_W1T,O_W2T,O_UT,O_VT,O_WS1T,O_WS2T,
                                 O_W1T+16384,O_W2T+49152,O_UT+16384,O_VT+16384,O_WS1T+32768,O_WS2T+49152,
                                 O_W1T+32768,O_W2T+98304,O_UT+32768,O_VT+32768,O_WS1T+65536,O_WS2T+98304,
                                 O_WR1T,O_WR2T,O_WF1T,O_WF2T,O_WF3T};
    constexpr int KK[NSEG]   = {128,128,128,128,256,128, 128,128,128,128,256,128,
                                128,128,128,128,256,128, 128,128,64,128,128};
    constexpr int NN[NSEG]   = {128,384,128,128,128,384, 128,384,128,128,128,384,
                                128,384,128,128,128,384, 128,64,128,128,5};
    constexpr int NP[NSEG]   = {128,384,128,128,128,384, 128,384,128,128,128,384,
                                128,384,128,128,128,384, 128,64,128,128,64};
    int t = blockIdx.x * blockDim.x + threadIdx.x;
    int bf = *flag;
    #pragma unroll
    for (int s = 0; s < NSEG; s++){
        int tot = NP[s] * KK[s];
        if (t < tot){
            int n = t / KK[s], k = t & (KK[s] - 1);     // K is pow2
            ushort hi = 0, lo = 0;
            if (n < NN[s]){
                int si = SOFF[s] + k * NN[s] + n;
                float w = bf ? b2f(((const ushort*)sp.p[SRC[s]])[si])
                             : ((const float*)sp.p[SRC[s]])[si];
                hi = f2b(w); lo = f2b(w - b2f(hi));
            }
            wb[DOFF[s] + t] = hi;
            wb[O_WTOT + DOFF[s] + t] = lo;
            return;
        }
        t -= tot;
    }
}
constexpr int WT_TOTAL = 598016;

__global__ void k_store_out(const float* __restrict__ src, void* __restrict__ dst, int n,
                            const int* __restrict__ flag){
    int t = blockIdx.x * blockDim.x + threadIdx.x;
    if (t >= n) return;
    float v = src[t];
    if (*flag) ((ushort*)dst)[t] = f2b(v);
    else       ((float*)dst)[t] = v;
}

// ---------------- utility ----------------
__global__ void k_zero_f(float* p, int n){
    int t = blockIdx.x * blockDim.x + threadIdx.x;
    if (t < n) p[t] = 0.f;
}
__global__ void k_zero_i(int* p, int n){
    int t = blockIdx.x * blockDim.x + threadIdx.x;
    if (t < n) p[t] = 0;
}
__global__ void k_init_s(const float* __restrict__ embed, const int* __restrict__ z,
                         float* __restrict__ s, ushort* __restrict__ shi,
                         ushort* __restrict__ slo){
    int t = blockIdx.x * blockDim.x + threadIdx.x;
    if (t >= N_ATOMS * FEAT) return;
    int n = t >> 7, f = t & 127;
    float v = embed[z[n] * FEAT + f];
    s[t] = v;
    ushort h = f2b(v); shi[t] = h; slo[t] = f2b(v - b2f(h));
}

// ---------------- geometry ----------------
__global__ void k_geom(const float* __restrict__ xyz, const int* __restrict__ nbrs,
                       float* __restrict__ fcb, float* __restrict__ unit,
                       float* __restrict__ G){
    int e = blockIdx.x * blockDim.x + threadIdx.x;
    if (e >= N_EDGES) return;
    int i = nbrs[2*e], j = nbrs[2*e+1];
    float rx = xyz[3*j]   - xyz[3*i];
    float ry = xyz[3*j+1] - xyz[3*i+1];
    float rz = xyz[3*j+2] - xyz[3*i+2];
    float d  = sqrtf(rx*rx + ry*ry + rz*rz + 1e-12f);
    float inv = 1.0f / d;
    unit[3*e] = rx*inv; unit[3*e+1] = ry*inv; unit[3*e+2] = rz*inv;
    float fc = (d < 5.0f) ? 0.5f * (cosf(PI_F * d * 0.2f) + 1.0f) : 0.0f;
    fcb[e] = fc;
    float base = PI_F * d * 0.2f;
    #pragma unroll
    for (int r = 0; r < N_RBF; r++)
        G[(size_t)e*N_RBF + r] = sinf((r+1) * base) * inv * fc;
}

// ---------------- CSR build ----------------
__global__ void k_hist(const int* __restrict__ nbrs, int* __restrict__ cnt){
    int e = blockIdx.x * blockDim.x + threadIdx.x;
    if (e < N_EDGES) atomicAdd(&cnt[nbrs[2*e]], 1);
}
__global__ void k_scan(const int* __restrict__ cnt, int* __restrict__ row, int* __restrict__ cur){
    __shared__ int ls[256];
    int t = threadIdx.x, base = t * 80;
    int s = 0;
    for (int k = 0; k < 80; k++){ int i = base + k; if (i < N_ATOMS) s += cnt[i]; }
    ls[t] = s; __syncthreads();
    for (int off = 1; off < 256; off <<= 1){
        int v = (t >= off) ? ls[t - off] : 0;
        __syncthreads();
        ls[t] += v;
        __syncthreads();
    }
    int run = ls[t] - s;
    for (int k = 0; k < 80; k++){
        int i = base + k;
        if (i < N_ATOMS){ row[i] = run; cur[i] = run; run += cnt[i]; }
    }
    if (t == 255) row[N_ATOMS] = ls[255];
}
__global__ void k_fill(const int* __restrict__ nbrs, int* __restrict__ cur, int* __restrict__ eid){
    int e = blockIdx.x * blockDim.x + threadIdx.x;
    if (e >= N_EDGES) return;
    int p = atomicAdd(&cur[nbrs[2*e]], 1);
    eid[p] = e;
}

// ---------------- split-bf16 MFMA GEMM, compile-time K ----------------
// C = act(A @ Bt^T + bias); A = Ahi+Alo (MxK), Bt = Bthi+Btlo (NpadxK)
// Ahi@Bhi + Ahi@Blo + Alo@Bhi. K templated -> full unroll in 128-chunks
// so all loads of a chunk issue before the MFMA chain (latency batching).
template<int KT>
__global__ __launch_bounds__(256) void k_gemm3t(
    const ushort* __restrict__ Ahi, const ushort* __restrict__ Alo,
    const ushort* __restrict__ Bthi, const ushort* __restrict__ Btlo,
    const float* __restrict__ bias, int M, int N, int act,
    float* __restrict__ Cf, ushort* __restrict__ Chi, ushort* __restrict__ Clo)
{
    int wave = threadIdx.x >> 6, lane = threadIdx.x & 63;
    int l15 = lane & 15, quad = lane >> 4;
    int m0 = blockIdx.y * 64 + wave * 16;
    int n0 = blockIdx.x * 64;
    const ushort* aph = Ahi  + (size_t)(m0 + l15) * KT + quad * 8;
    const ushort* apl = Alo  + (size_t)(m0 + l15) * KT + quad * 8;
    const ushort* bph = Bthi + (size_t)(n0 + l15) * KT + quad * 8;
    const ushort* bpl = Btlo + (size_t)(n0 + l15) * KT + quad * 8;
    f32x4 acc[4];
    #pragma unroll
    for (int c = 0; c < 4; c++) acc[c] = (f32x4){0.f, 0.f, 0.f, 0.f};
    constexpr int KIN = (KT < 128) ? KT : 128;
    #pragma unroll 1
    for (int kb = 0; kb < KT; kb += 128) {
        #pragma unroll
        for (int ko = 0; ko < KIN; ko += 32) {
            int k0 = kb + ko;
            bf16x8 ah = *reinterpret_cast<const bf16x8*>(aph + k0);
            bf16x8 al = *reinterpret_cast<const bf16x8*>(apl + k0);
            #pragma unroll
            for (int c = 0; c < 4; c++) {
                bf16x8 bh = *reinterpret_cast<const bf16x8*>(bph + (size_t)c * 16 * KT + k0);
                bf16x8 bl = *reinterpret_cast<const bf16x8*>(bpl + (size_t)c * 16 * KT + k0);
                acc[c] = __builtin_amdgcn_mfma_f32_16x16x32_bf16(al, bh, acc[c], 0, 0, 0);
                acc[c] = __builtin_amdgcn_mfma_f32_16x16x32_bf16(ah, bl, acc[c], 0, 0, 0);
                acc[c] = __builtin_amdgcn_mfma_f32_16x16x32_bf16(ah, bh, acc[c], 0, 0, 0);
            }
        }
    }
    int row_base = m0 + quad * 4;
    #pragma unroll
    for (int c = 0; c < 4; c++) {
        int col = n0 + c * 16 + l15;
        #pragma unroll
        for (int r = 0; r < 4; r++) {
            int row = row_base + r;
            if (row < M && col < N) {
                float v = acc[c][r];
                if (bias) v += bias[col];
                if (act)  v = v / (1.f + expf(-v));
                size_t idx = (size_t)row * N + col;
                if (Cf)  Cf[idx] = v;
                if (Chi) { ushort h = f2b(v); Chi[idx] = h; Clo[idx] = f2b(v - b2f(h)); }
            }
        }
    }
}

// ---------------- edge gather-reduce (f32, no atomics) ----------------
__global__ __launch_bounds__(128) void k_edge3(
    const float* __restrict__ phi, const float* __restrict__ vin,
    const float* __restrict__ unit, const float* __restrict__ fcb,
    const float* __restrict__ G,
    const int* __restrict__ nbrs, const int* __restrict__ row, const int* __restrict__ eid,
    const float* __restrict__ Wd, const float* __restrict__ bd,
    float* __restrict__ s, ushort* __restrict__ vhi, ushort* __restrict__ vlo)
{
    int i = blockIdx.x, f = threadIdx.x;
    float wdr[3 * N_RBF];
    #pragma unroll
    for (int r = 0; r < N_RBF; r++) {
        wdr[r]           = Wd[r*384 + f];
        wdr[N_RBF + r]   = Wd[r*384 + 128 + f];
        wdr[2*N_RBF + r] = Wd[r*384 + 256 + f];
    }
    float bd0 = bd[f], bd1 = bd[128 + f], bd2 = bd[256 + f];
    float sacc = 0.f, va0 = 0.f, va1 = 0.f, va2 = 0.f;
    int beg = row[i], end = row[i + 1];
    for (int idx = beg; idx < end; idx++) {
        int e = eid[idx];
        int j = nbrs[2*e + 1];
        float fc = fcb[e];
        float w0 = bd0 * fc, w1 = bd1 * fc, w2 = bd2 * fc;
        const float* g = G + (size_t)e * N_RBF;
        #pragma unroll
        for (int r = 0; r < N_RBF; r++) {
            float gr = g[r];
            w0 = fmaf(gr, wdr[r],           w0);
            w1 = fmaf(gr, wdr[N_RBF + r],   w1);
            w2 = fmaf(gr, wdr[2*N_RBF + r], w2);
        }
        size_t pj = (size_t)j * 384;
        float inv0 = phi[pj + f]       * w0;
        float inv1 = phi[pj + 128 + f] * w1;
        float inv2 = phi[pj + 256 + f] * w2;
        float ux = unit[3*e], uy = unit[3*e+1], uz = unit[3*e+2];
        size_t vj = (size_t)j * 384 + f;
        sacc += inv1;
        va0 = fmaf(inv0, vin[vj],       fmaf(ux, inv2, va0));
        va1 = fmaf(inv0, vin[vj + 128], fmaf(uy, inv2, va1));
        va2 = fmaf(inv0, vin[vj + 256], fmaf(uz, inv2, va2));
    }
    s[(size_t)i * FEAT + f] += sacc;
    size_t vi = (size_t)i * 384 + f;
    float n0 = vin[vi] + va0, n1 = vin[vi + 128] + va1, n2 = vin[vi + 256] + va2;
    ushort h;
    h = f2b(n0); vhi[vi]       = h; vlo[vi]       = f2b(n0 - b2f(h));
    h = f2b(n1); vhi[vi + 128] = h; vlo[vi + 128] = f2b(n1 - b2f(h));
    h = f2b(n2); vhi[vi + 256] = h; vlo[vi + 256] = f2b(n2 - b2f(h));
}

// ---------------- vnorm + concat -> CAT hi/lo ----------------
__global__ void k_vnorm_cat(const float* __restrict__ s, const float* __restrict__ vv,
                            ushort* __restrict__ chi, ushort* __restrict__ clo){
    int t = blockIdx.x * blockDim.x + threadIdx.x;
    if (t >= N_ATOMS * FEAT) return;
    int n = t >> 7, g = t & 127;
    size_t b = (size_t)n * 384 + g;
    float a0 = vv[b], a1 = vv[b + 128], a2 = vv[b + 256];
    float nr = sqrtf(a0*a0 + a1*a1 + a2*a2 + 1e-12f);
    float sv = s[t];
    size_t c0 = (size_t)n * 256 + g;
    ushort h;
    h = f2b(sv); chi[c0]       = h; clo[c0]       = f2b(sv - b2f(h));
    h = f2b(nr); chi[c0 + 128] = h; clo[c0 + 128] = f2b(nr - b2f(h));
}

// ---------------- gated update ----------------
__global__ void k_update(const float* __restrict__ uv, const float* __restrict__ vv,
                         const float* __restrict__ spl,
                         const ushort* __restrict__ vhi, const ushort* __restrict__ vlo,
                         float* __restrict__ s, float* __restrict__ v,
                         ushort* __restrict__ shi, ushort* __restrict__ slo){
    int t = blockIdx.x * blockDim.x + threadIdx.x;
    if (t >= N_ATOMS * FEAT) return;
    int n = t >> 7, g = t & 127;
    size_t sp = (size_t)n * 384 + g;
    float avv = spl[sp], asv = spl[sp + 128], ass = spl[sp + 256];
    float dot = 0.f;
    size_t b = (size_t)n * 384 + g;
    #pragma unroll
    for (int d = 0; d < 3; d++) {
        size_t idx = b + (size_t)d * 128;
        float u  = uv[idx];
        float w  = vv[idx];
        float vb = b2f(vhi[idx]) + b2f(vlo[idx]);
        dot = fmaf(u, w, dot);
        v[idx] = vb + u * avv;
    }
    float ns = s[t] + dot * asv + ass;
    s[t] = ns;
    ushort h = f2b(ns); shi[t] = h; slo[t] = f2b(ns - b2f(h));
}

// ---------------- host ----------------
struct Pair { ushort* hi; ushort* lo; };

static inline void gemm3(Pair A, Pair B, const float* bias,
                         int M, int K, int N, int Npad, int act,
                         float* Cf, Pair C, hipStream_t s){
    dim3 g(Npad / 64, (M + 63) / 64), b(256);
    switch (K) {
    case 64:  k_gemm3t<64> <<<g, b, 0, s>>>(A.hi, A.lo, B.hi, B.lo, bias, M, N, act, Cf, C.hi, C.lo); break;
    case 128: k_gemm3t<128><<<g, b, 0, s>>>(A.hi, A.lo, B.hi, B.lo, bias, M, N, act, Cf, C.hi, C.lo); break;
    case 256: k_gemm3t<256><<<g, b, 0, s>>>(A.hi, A.lo, B.hi, B.lo, bias, M, N, act, Cf, C.hi, C.lo); break;
    }
}

extern "C" void kernel_launch(void* const* d_in, const int* in_sizes, int n_in,
                              void* d_out, int out_size, void* d_ws, size_t ws_size,
                              hipStream_t stream) {
    float* ws = (float*)d_ws;
    int* flag = (int*)d_ws;
    const int* z    = (const int*)d_in[1];
    const int* nbrs = (const int*)d_in[2];

    k_detect<<<1, 64, 0, stream>>>((const unsigned int*)d_in[0], flag);

    // mega converts (2 launches instead of 36)
    P13 cp; {
        const int cidx[13] = {0,3,5,7,8,9,13,15,17,19,21,23,25};
        for (int i = 0; i < 13; i++) cp.p[i] = d_in[cidx[i]];
    }
    k_cvt_all<<<(100517 + 255)/256, 256, 0, stream>>>(cp, ws, flag);

    ushort* wb = (ushort*)(ws + H_WT);
    P11 wp; {
        const int widx[11] = {4,6,10,11,12,14,16,18,20,22,24};
        for (int i = 0; i < 11; i++) wp.p[i] = d_in[widx[i]];
    }
    k_wt_all<<<(WT_TOTAL + 255)/256, 256, 0, stream>>>(wp, wb, flag);

    // geometry + CSR
    k_geom<<<(N_EDGES+255)/256, 256, 0, stream>>>(ws + F_XYZ, nbrs, ws + F_FC, ws + F_UNIT, ws + F_G);
    int* cnt = (int*)(ws + F_CNT); int* row = (int*)(ws + F_ROW);
    int* cur = (int*)(ws + F_CUR); int* eid = (int*)(ws + F_EID);
    k_zero_i<<<(N_ATOMS+255)/256, 256, 0, stream>>>(cnt, N_ATOMS);
    k_hist<<<(N_EDGES+255)/256, 256, 0, stream>>>(nbrs, cnt);
    k_scan<<<1, 256, 0, stream>>>(cnt, row, cur);
    k_fill<<<(N_EDGES+255)/256, 256, 0, stream>>>(nbrs, cur, eid);

    float* S   = ws + F_S;
    float* V   = ws + F_V;
    float* PHI = ws + F_PHI;       // phi f32, then uv f32
    float* VV  = ws + F_VV;
    float* SPL = ws + F_SPL;
    auto WPW = [&](size_t off){ return Pair{ wb + off, wb + O_WTOT + off }; };
    Pair SHL { (ushort*)(ws + H_SHI),  (ushort*)(ws + H_SLO)  };
    Pair VHL { (ushort*)(ws + H_VHI),  (ushort*)(ws + H_VLO)  };
    Pair HA  { (ushort*)(ws + H_HAHI), (ushort*)(ws + H_HALO) };
    Pair HB  { (ushort*)(ws + H_HBHI), (ushort*)(ws + H_HBLO) };
    Pair AF  { (ushort*)(ws + H_AFHI), (ushort*)(ws + H_AFLO) };
    Pair CAT { (ushort*)(ws + F_SPL),  (ushort*)(ws + F_SPL) + (size_t)M20P*256 };
    Pair NOP { nullptr, nullptr };

    k_init_s<<<(N_ATOMS*FEAT+255)/256, 256, 0, stream>>>(ws + F_EMB, z, S, SHL.hi, SHL.lo);
    k_zero_f<<<(60000*FEAT+255)/256, 256, 0, stream>>>(V, 60000*FEAT);

    for (int l = 0; l < N_CONV; l++) {
        gemm3(SHL, WPW(O_W1T + l*16384), ws + F_B1 + l*128, N_ATOMS, 128, 128, 128, 1, nullptr, HA, stream);
        gemm3(HA,  WPW(O_W2T + l*49152), ws + F_B2 + l*384, N_ATOMS, 128, 384, 384, 0, PHI, NOP, stream);
        k_edge3<<<N_ATOMS, 128, 0, stream>>>(PHI, V, ws + F_UNIT, ws + F_FC, ws + F_G,
                                             nbrs, row, eid,
                                             ws + F_WD + (size_t)l*20*384, ws + F_BD + l*384,
                                             S, VHL.hi, VHL.lo);
        gemm3(VHL, WPW(O_UT + l*16384), nullptr, 60000, 128, 128, 128, 0, PHI, NOP, stream);
        gemm3(VHL, WPW(O_VT + l*16384), nullptr, 60000, 128, 128, 128, 0, VV,  NOP, stream);
        k_vnorm_cat<<<(N_ATOMS*FEAT+255)/256, 256, 0, stream>>>(S, VV, CAT.hi, CAT.lo);
        gemm3(CAT, WPW(O_WS1T + l*32768), ws + F_BS1 + l*128, N_ATOMS, 256, 128, 128, 1, nullptr, HB, stream);
        gemm3(HB,  WPW(O_WS2T + l*49152), ws + F_BS2 + l*384, N_ATOMS, 128, 384, 384, 0, SPL, NOP, stream);
        k_update<<<(N_ATOMS*FEAT+255)/256, 256, 0, stream>>>(PHI, VV, SPL, VHL.hi, VHL.lo,
                                                             S, V, SHL.hi, SHL.lo);
    }

    // readout
    gemm3(SHL, WPW(O_WR1T), ws + F_BR1, N_ATOMS, 128, 128, 128, 1, nullptr, HA, stream);
    gemm3(HA,  WPW(O_WR2T), ws + F_BR2, N_ATOMS, 128,  64,  64, 0, nullptr, AF, stream);
    gemm3(AF,  WPW(O_WF1T), ws + F_BF1, N_ATOMS,  64, 128, 128, 1, nullptr, HB, stream);
    gemm3(HB,  WPW(O_WF2T), ws + F_BF2, N_ATOMS, 128, 128, 128, 1, nullptr, HA, stream);
    gemm3(HA,  WPW(O_WF3T), ws + F_BF3, N_ATOMS, 128, N_OUT_, 64, 0, ws + F_OUT, NOP, stream);

    k_store_out<<<(N_ATOMS*N_OUT_+255)/256, 256, 0, stream>>>(ws + F_OUT, d_out, N_ATOMS*N_OUT_, flag);
}

// Round 5
// 1444.512 us; speedup vs baseline: 2.8581x; 1.1278x over previous
//
#include <hip/hip_runtime.h>
#include <hip/hip_bf16.h>
#include <math.h>

#define N_ATOMS 20000
#define N_EDGES 320000
#define FEAT 128
#define N_RBF 20
#define N_CONV 3
#define N_OUT_ 5
#define PI_F 3.14159265358979f
#define M20P 20032
#define M60P 60032

typedef unsigned short ushort;
typedef __bf16 bf16x8 __attribute__((ext_vector_type(8)));
typedef float f32x4 __attribute__((ext_vector_type(4)));

__device__ __forceinline__ float b2f(ushort u){ return __uint_as_float(((unsigned)u) << 16); }
__device__ __forceinline__ ushort f2b(float x){
    unsigned u = __float_as_uint(x);
    return (ushort)((u + 0x7FFFu + ((u >> 16) & 1u)) >> 16);   // RNE
}

// ---------------- workspace layout (float slots) ----------------
constexpr size_t rnd64(size_t x){ return (x + 63) & ~size_t(63); }
constexpr size_t F_XYZ  = 64;                                  // flag at ws[0]
constexpr size_t F_EMB  = rnd64(F_XYZ + 60000);
constexpr size_t F_B1   = rnd64(F_EMB + 12800);
constexpr size_t F_B2   = rnd64(F_B1  + 3*128);
constexpr size_t F_WD   = rnd64(F_B2  + 3*384);
constexpr size_t F_BD   = rnd64(F_WD  + 3*20*384);
constexpr size_t F_BS1  = rnd64(F_BD  + 3*384);
constexpr size_t F_BS2  = rnd64(F_BS1 + 3*128);
constexpr size_t F_BR1  = rnd64(F_BS2 + 3*384);
constexpr size_t F_BR2  = rnd64(F_BR1 + 128);
constexpr size_t F_BF1  = rnd64(F_BR2 + 64);
constexpr size_t F_BF2  = rnd64(F_BF1 + 128);
constexpr size_t F_BF3  = rnd64(F_BF2 + 128);
constexpr size_t F_FC   = rnd64(F_BF3 + 8);
constexpr size_t F_UNIT = rnd64(F_FC   + N_EDGES);
constexpr size_t F_G    = rnd64(F_UNIT + 3*N_EDGES);
constexpr size_t F_CNT  = rnd64(F_G    + (size_t)N_EDGES*N_RBF);
constexpr size_t F_ROW  = rnd64(F_CNT  + N_ATOMS);
constexpr size_t F_CUR  = rnd64(F_ROW  + N_ATOMS + 1);
constexpr size_t F_EID  = rnd64(F_CUR  + N_ATOMS);
constexpr size_t F_S    = rnd64(F_EID  + N_EDGES);
constexpr size_t F_V    = rnd64(F_S    + (size_t)N_ATOMS*FEAT);
constexpr size_t F_PHI  = rnd64(F_V    + (size_t)60000*FEAT);     // phi f32, later uv f32
constexpr size_t F_VV   = rnd64(F_PHI  + (size_t)N_ATOMS*384);
constexpr size_t F_SPL  = rnd64(F_VV   + (size_t)60000*FEAT);     // split f32; CAT hi/lo aliases
constexpr size_t F_OUT  = rnd64(F_SPL  + (size_t)N_ATOMS*384);
// bf16 hi/lo pair buffers (slot counts = elems/2)
constexpr size_t H_SHI  = rnd64(F_OUT  + N_ATOMS*N_OUT_);
constexpr size_t H_SLO  = rnd64(H_SHI  + (size_t)M20P*128/2);
constexpr size_t H_VHI  = rnd64(H_SLO  + (size_t)M20P*128/2);
constexpr size_t H_VLO  = rnd64(H_VHI  + (size_t)M60P*128/2);
constexpr size_t H_HAHI = rnd64(H_VLO  + (size_t)M60P*128/2);
constexpr size_t H_HALO = rnd64(H_HAHI + (size_t)M20P*128/2);
constexpr size_t H_HBHI = rnd64(H_HALO + (size_t)M20P*128/2);
constexpr size_t H_HBLO = rnd64(H_HBHI + (size_t)M20P*128/2);
constexpr size_t H_AFHI = rnd64(H_HBLO + (size_t)M20P*128/2);
constexpr size_t H_AFLO = rnd64(H_AFHI + (size_t)M20P*64/2);
constexpr size_t H_WT   = rnd64(H_AFLO + (size_t)M20P*64/2);
// weight offsets (ushort elems within hi half; lo = +O_WTOT)
constexpr size_t O_W1T=0, O_W2T=49152, O_UT=196608, O_VT=245760, O_WS1T=294912,
                 O_WS2T=393216, O_WR1T=540672, O_WR2T=557056, O_WF1T=565248,
                 O_WF2T=573440, O_WF3T=589824, O_WTOT=598016;

// ---------------- dtype detection ----------------
__global__ void k_detect(const unsigned int* __restrict__ bits, int* flag){
    __shared__ int cnt;
    if (threadIdx.x == 0) cnt = 0;
    __syncthreads();
    unsigned int lo = bits[threadIdx.x] & 0xFFFFu;
    if (lo >= 0x3000u && lo <= 0x4100u) atomicAdd(&cnt, 1);
    __syncthreads();
    if (threadIdx.x == 0) *flag = (cnt >= 48) ? 1 : 0;
}

// ---------------- mega f32-convert (13 segments, 1 launch) ----------------
struct P13 { const void* p[13]; };
__global__ void k_cvt_all(P13 sp, float* __restrict__ ws, const int* __restrict__ flag){
    constexpr int   NSEG = 13;
    constexpr int    SZ[NSEG] = {60000,12800,384,1152,23040,1152,384,1152,128,64,128,128,5};
    constexpr size_t DO_[NSEG]= {F_XYZ,F_EMB,F_B1,F_B2,F_WD,F_BD,F_BS1,F_BS2,F_BR1,F_BR2,F_BF1,F_BF2,F_BF3};
    int t = blockIdx.x * blockDim.x + threadIdx.x;
    int bf = *flag;
    #pragma unroll
    for (int s = 0; s < NSEG; s++){
        if (t < SZ[s]){
            float v = bf ? b2f(((const ushort*)sp.p[s])[t]) : ((const float*)sp.p[s])[t];
            ws[DO_[s] + t] = v;
            return;
        }
        t -= SZ[s];
    }
}

// ---------------- mega weight transpose hi/lo (23 segments, 1 launch) ----------------
struct P11 { const void* p[11]; };
__global__ void k_wt_all(P11 sp, ushort* __restrict__ wb, const int* __restrict__ flag){
    constexpr int NSEG = 23;
    constexpr int SRC[NSEG]  = {0,1,2,3,4,5, 0,1,2,3,4,5, 0,1,2,3,4,5, 6,7,8,9,10};
    constexpr int SOFF[NSEG] = {0,0,0,0,0,0, 16384,49152,16384,16384,32768,49152,
                                32768,98304,32768,32768,65536,98304, 0,0,0,0,0};
    constexpr size_t DOFF[NSEG]={O_W1T,O_W2T,O_UT,O_VT,O_WS1T,O_WS2T,
                                 O_W1T+16384,O_W2T+49152,O_UT+16384,O_VT+16384,O_WS1T+32768,O_WS2T+49152,
                                 O_W1T+32768,O_W2T+98304,O_UT+32768,O_VT+32768,O_WS1T+65536,O_WS2T+98304,
                                 O_WR1T,O_WR2T,O_WF1T,O_WF2T,O_WF3T};
    constexpr int KK[NSEG]   = {128,128,128,128,256,128, 128,128,128,128,256,128,
                                128,128,128,128,256,128, 128,128,64,128,128};
    constexpr int NN[NSEG]   = {128,384,128,128,128,384, 128,384,128,128,128,384,
                                128,384,128,128,128,384, 128,64,128,128,5};
    constexpr int NP[NSEG]   = {128,384,128,128,128,384, 128,384,128,128,128,384,
                                128,384,128,128,128,384, 128,64,128,128,64};
    int t = blockIdx.x * blockDim.x + threadIdx.x;
    int bf = *flag;
    #pragma unroll
    for (int s = 0; s < NSEG; s++){
        int tot = NP[s] * KK[s];
        if (t < tot){
            int n = t / KK[s], k = t & (KK[s] - 1);
            ushort hi = 0, lo = 0;
            if (n < NN[s]){
                int si = SOFF[s] + k * NN[s] + n;
                float w = bf ? b2f(((const ushort*)sp.p[SRC[s]])[si])
                             : ((const float*)sp.p[SRC[s]])[si];
                hi = f2b(w); lo = f2b(w - b2f(hi));
            }
            wb[DOFF[s] + t] = hi;
            wb[O_WTOT + DOFF[s] + t] = lo;
            return;
        }
        t -= tot;
    }
}
constexpr int WT_TOTAL = 598016;

__global__ void k_store_out(const float* __restrict__ src, void* __restrict__ dst, int n,
                            const int* __restrict__ flag){
    int t = blockIdx.x * blockDim.x + threadIdx.x;
    if (t >= n) return;
    float v = src[t];
    if (*flag) ((ushort*)dst)[t] = f2b(v);
    else       ((float*)dst)[t] = v;
}

// ---------------- utility ----------------
__global__ void k_zero_f(float* p, int n){
    int t = blockIdx.x * blockDim.x + threadIdx.x;
    if (t < n) p[t] = 0.f;
}
__global__ void k_zero_i(int* p, int n){
    int t = blockIdx.x * blockDim.x + threadIdx.x;
    if (t < n) p[t] = 0;
}
__global__ void k_init_s(const float* __restrict__ embed, const int* __restrict__ z,
                         float* __restrict__ s, ushort* __restrict__ shi,
                         ushort* __restrict__ slo){
    int t = blockIdx.x * blockDim.x + threadIdx.x;
    if (t >= N_ATOMS * FEAT) return;
    int n = t >> 7, f = t & 127;
    float v = embed[z[n] * FEAT + f];
    s[t] = v;
    ushort h = f2b(v); shi[t] = h; slo[t] = f2b(v - b2f(h));
}

// ---------------- geometry (sine recurrence: sin((r+1)b) via Chebyshev) ------
__global__ void k_geom(const float* __restrict__ xyz, const int* __restrict__ nbrs,
                       float* __restrict__ fcb, float* __restrict__ unit,
                       float* __restrict__ G){
    int e = blockIdx.x * blockDim.x + threadIdx.x;
    if (e >= N_EDGES) return;
    int i = nbrs[2*e], j = nbrs[2*e+1];
    float rx = xyz[3*j]   - xyz[3*i];
    float ry = xyz[3*j+1] - xyz[3*i+1];
    float rz = xyz[3*j+2] - xyz[3*i+2];
    float d  = sqrtf(rx*rx + ry*ry + rz*rz + 1e-12f);
    float inv = 1.0f / d;
    unit[3*e] = rx*inv; unit[3*e+1] = ry*inv; unit[3*e+2] = rz*inv;
    float b  = PI_F * d * 0.2f;
    float sb = sinf(b), cb = cosf(b);
    float fc = (d < 5.0f) ? 0.5f * (cb + 1.0f) : 0.0f;
    fcb[e] = fc;
    float scale = inv * fc, c2 = 2.0f * cb;
    float sp = 0.f, sc = sb;                 // sin(0), sin(1*b)
    float* g = G + (size_t)e * N_RBF;
    #pragma unroll
    for (int r = 0; r < N_RBF; r++){
        g[r] = sc * scale;
        float sn = c2 * sc - sp;             // sin((r+2)b)
        sp = sc; sc = sn;
    }
}

// ---------------- CSR build ----------------
__global__ void k_hist(const int* __restrict__ nbrs, int* __restrict__ cnt){
    int e = blockIdx.x * blockDim.x + threadIdx.x;
    if (e < N_EDGES) atomicAdd(&cnt[nbrs[2*e]], 1);
}
__global__ void k_scan(const int* __restrict__ cnt, int* __restrict__ row, int* __restrict__ cur){
    __shared__ int ls[256];
    int t = threadIdx.x, base = t * 80;
    int s = 0;
    for (int k = 0; k < 80; k++){ int i = base + k; if (i < N_ATOMS) s += cnt[i]; }
    ls[t] = s; __syncthreads();
    for (int off = 1; off < 256; off <<= 1){
        int v = (t >= off) ? ls[t - off] : 0;
        __syncthreads();
        ls[t] += v;
        __syncthreads();
    }
    int run = ls[t] - s;
    for (int k = 0; k < 80; k++){
        int i = base + k;
        if (i < N_ATOMS){ row[i] = run; cur[i] = run; run += cnt[i]; }
    }
    if (t == 255) row[N_ATOMS] = ls[255];
}
__global__ void k_fill(const int* __restrict__ nbrs, int* __restrict__ cur, int* __restrict__ eid){
    int e = blockIdx.x * blockDim.x + threadIdx.x;
    if (e >= N_EDGES) return;
    int p = atomicAdd(&cur[nbrs[2*e]], 1);
    eid[p] = e;
}

// ---------------- split-bf16 MFMA GEMM, fat wave tile 32x64 ----------------
// C = act(A @ Bt^T + bias); wave computes 32 rows x 64 cols (2 A-frags x 4 B-frags)
// block = 4 waves stacked over rows -> 128 rows x 64 cols per block.
// 24 MFMA : 12 loads per k-chunk (vs 12:10 in the thin-tile version).
template<int KT>
__global__ __launch_bounds__(256) void k_gemm3t(
    const ushort* __restrict__ Ahi, const ushort* __restrict__ Alo,
    const ushort* __restrict__ Bthi, const ushort* __restrict__ Btlo,
    const float* __restrict__ bias, int M, int N, int act,
    float* __restrict__ Cf, ushort* __restrict__ Chi, ushort* __restrict__ Clo)
{
    int wave = threadIdx.x >> 6, lane = threadIdx.x & 63;
    int l15 = lane & 15, quad = lane >> 4;
    int m0 = blockIdx.y * 128 + wave * 32;
    int n0 = blockIdx.x * 64;
    const ushort* aph = Ahi  + (size_t)(m0 + l15) * KT + quad * 8;
    const ushort* apl = Alo  + (size_t)(m0 + l15) * KT + quad * 8;
    const ushort* bph = Bthi + (size_t)(n0 + l15) * KT + quad * 8;
    const ushort* bpl = Btlo + (size_t)(n0 + l15) * KT + quad * 8;
    f32x4 acc[2][4];
    #pragma unroll
    for (int r = 0; r < 2; r++)
        #pragma unroll
        for (int c = 0; c < 4; c++) acc[r][c] = (f32x4){0.f, 0.f, 0.f, 0.f};
    #pragma unroll
    for (int k0 = 0; k0 < KT; k0 += 32) {
        bf16x8 ah0 = *reinterpret_cast<const bf16x8*>(aph + k0);
        bf16x8 al0 = *reinterpret_cast<const bf16x8*>(apl + k0);
        bf16x8 ah1 = *reinterpret_cast<const bf16x8*>(aph + (size_t)16 * KT + k0);
        bf16x8 al1 = *reinterpret_cast<const bf16x8*>(apl + (size_t)16 * KT + k0);
        #pragma unroll
        for (int c = 0; c < 4; c++) {
            bf16x8 bh = *reinterpret_cast<const bf16x8*>(bph + (size_t)c * 16 * KT + k0);
            bf16x8 bl = *reinterpret_cast<const bf16x8*>(bpl + (size_t)c * 16 * KT + k0);
            acc[0][c] = __builtin_amdgcn_mfma_f32_16x16x32_bf16(al0, bh, acc[0][c], 0, 0, 0);
            acc[0][c] = __builtin_amdgcn_mfma_f32_16x16x32_bf16(ah0, bl, acc[0][c], 0, 0, 0);
            acc[0][c] = __builtin_amdgcn_mfma_f32_16x16x32_bf16(ah0, bh, acc[0][c], 0, 0, 0);
            acc[1][c] = __builtin_amdgcn_mfma_f32_16x16x32_bf16(al1, bh, acc[1][c], 0, 0, 0);
            acc[1][c] = __builtin_amdgcn_mfma_f32_16x16x32_bf16(ah1, bl, acc[1][c], 0, 0, 0);
            acc[1][c] = __builtin_amdgcn_mfma_f32_16x16x32_bf16(ah1, bh, acc[1][c], 0, 0, 0);
        }
    }
    #pragma unroll
    for (int rr = 0; rr < 2; rr++) {
        int row_base = m0 + rr * 16 + quad * 4;
        #pragma unroll
        for (int c = 0; c < 4; c++) {
            int col = n0 + c * 16 + l15;
            #pragma unroll
            for (int r = 0; r < 4; r++) {
                int row = row_base + r;
                if (row < M && col < N) {
                    float v = acc[rr][c][r];
                    if (bias) v += bias[col];
                    if (act)  v = v / (1.f + expf(-v));
                    size_t idx = (size_t)row * N + col;
                    if (Cf)  Cf[idx] = v;
                    if (Chi) { ushort h = f2b(v); Chi[idx] = h; Clo[idx] = f2b(v - b2f(h)); }
                }
            }
        }
    }
}

// ---------------- dual GEMM: C1 = A@B1^T, C2 = A@B2^T (shared A read) -------
// For uv/vv: A = post-message v (60000x128), B1=U^T, B2=V^T. f32 outputs.
__global__ __launch_bounds__(256) void k_gemm3_dual(
    const ushort* __restrict__ Ahi, const ushort* __restrict__ Alo,
    const ushort* __restrict__ B1hi, const ushort* __restrict__ B1lo,
    const ushort* __restrict__ B2hi, const ushort* __restrict__ B2lo,
    int M, float* __restrict__ C1, float* __restrict__ C2)
{
    constexpr int KT = 128, N = 128;
    int wave = threadIdx.x >> 6, lane = threadIdx.x & 63;
    int l15 = lane & 15, quad = lane >> 4;
    int m0 = blockIdx.y * 128 + wave * 32;
    int n0 = blockIdx.x * 64;
    const ushort* aph = Ahi  + (size_t)(m0 + l15) * KT + quad * 8;
    const ushort* apl = Alo  + (size_t)(m0 + l15) * KT + quad * 8;
    const ushort* b1h = B1hi + (size_t)(n0 + l15) * KT + quad * 8;
    const ushort* b1l = B1lo + (size_t)(n0 + l15) * KT + quad * 8;
    const ushort* b2h = B2hi + (size_t)(n0 + l15) * KT + quad * 8;
    const ushort* b2l = B2lo + (size_t)(n0 + l15) * KT + quad * 8;
    f32x4 acc1[2][4], acc2[2][4];
    #pragma unroll
    for (int r = 0; r < 2; r++)
        #pragma unroll
        for (int c = 0; c < 4; c++) {
            acc1[r][c] = (f32x4){0.f,0.f,0.f,0.f};
            acc2[r][c] = (f32x4){0.f,0.f,0.f,0.f};
        }
    #pragma unroll
    for (int k0 = 0; k0 < KT; k0 += 32) {
        bf16x8 ah0 = *reinterpret_cast<const bf16x8*>(aph + k0);
        bf16x8 al0 = *reinterpret_cast<const bf16x8*>(apl + k0);
        bf16x8 ah1 = *reinterpret_cast<const bf16x8*>(aph + (size_t)16 * KT + k0);
        bf16x8 al1 = *reinterpret_cast<const bf16x8*>(apl + (size_t)16 * KT + k0);
        #pragma unroll
        for (int c = 0; c < 4; c++) {
            bf16x8 bh = *reinterpret_cast<const bf16x8*>(b1h + (size_t)c * 16 * KT + k0);
            bf16x8 bl = *reinterpret_cast<const bf16x8*>(b1l + (size_t)c * 16 * KT + k0);
            acc1[0][c] = __builtin_amdgcn_mfma_f32_16x16x32_bf16(al0, bh, acc1[0][c], 0, 0, 0);
            acc1[0][c] = __builtin_amdgcn_mfma_f32_16x16x32_bf16(ah0, bl, acc1[0][c], 0, 0, 0);
            acc1[0][c] = __builtin_amdgcn_mfma_f32_16x16x32_bf16(ah0, bh, acc1[0][c], 0, 0, 0);
            acc1[1][c] = __builtin_amdgcn_mfma_f32_16x16x32_bf16(al1, bh, acc1[1][c], 0, 0, 0);
            acc1[1][c] = __builtin_amdgcn_mfma_f32_16x16x32_bf16(ah1, bl, acc1[1][c], 0, 0, 0);
            acc1[1][c] = __builtin_amdgcn_mfma_f32_16x16x32_bf16(ah1, bh, acc1[1][c], 0, 0, 0);
        }
        #pragma unroll
        for (int c = 0; c < 4; c++) {
            bf16x8 bh = *reinterpret_cast<const bf16x8*>(b2h + (size_t)c * 16 * KT + k0);
            bf16x8 bl = *reinterpret_cast<const bf16x8*>(b2l + (size_t)c * 16 * KT + k0);
            acc2[0][c] = __builtin_amdgcn_mfma_f32_16x16x32_bf16(al0, bh, acc2[0][c], 0, 0, 0);
            acc2[0][c] = __builtin_amdgcn_mfma_f32_16x16x32_bf16(ah0, bl, acc2[0][c], 0, 0, 0);
            acc2[0][c] = __builtin_amdgcn_mfma_f32_16x16x32_bf16(ah0, bh, acc2[0][c], 0, 0, 0);
            acc2[1][c] = __builtin_amdgcn_mfma_f32_16x16x32_bf16(al1, bh, acc2[1][c], 0, 0, 0);
            acc2[1][c] = __builtin_amdgcn_mfma_f32_16x16x32_bf16(ah1, bl, acc2[1][c], 0, 0, 0);
            acc2[1][c] = __builtin_amdgcn_mfma_f32_16x16x32_bf16(ah1, bh, acc2[1][c], 0, 0, 0);
        }
    }
    #pragma unroll
    for (int rr = 0; rr < 2; rr++) {
        int row_base = m0 + rr * 16 + quad * 4;
        #pragma unroll
        for (int c = 0; c < 4; c++) {
            int col = n0 + c * 16 + l15;
            #pragma unroll
            for (int r = 0; r < 4; r++) {
                int row = row_base + r;
                if (row < M) {
                    size_t idx = (size_t)row * N + col;
                    C1[idx] = acc1[rr][c][r];
                    C2[idx] = acc2[rr][c][r];
                }
            }
        }
    }
}

// ---------------- edge gather-reduce (f32, no atomics) ----------------
__global__ __launch_bounds__(128) void k_edge3(
    const float* __restrict__ phi, const float* __restrict__ vin,
    const float* __restrict__ unit, const float* __restrict__ fcb,
    const float* __restrict__ G,
    const int* __restrict__ nbrs, const int* __restrict__ row, const int* __restrict__ eid,
    const float* __restrict__ Wd, const float* __restrict__ bd,
    float* __restrict__ s, ushort* __restrict__ vhi, ushort* __restrict__ vlo)
{
    int i = blockIdx.x, f = threadIdx.x;
    float wdr[3 * N_RBF];
    #pragma unroll
    for (int r = 0; r < N_RBF; r++) {
        wdr[r]           = Wd[r*384 + f];
        wdr[N_RBF + r]   = Wd[r*384 + 128 + f];
        wdr[2*N_RBF + r] = Wd[r*384 + 256 + f];
    }
    float bd0 = bd[f], bd1 = bd[128 + f], bd2 = bd[256 + f];
    float sacc = 0.f, va0 = 0.f, va1 = 0.f, va2 = 0.f;
    int beg = row[i], end = row[i + 1];
    for (int idx = beg; idx < end; idx++) {
        int e = eid[idx];
        int j = nbrs[2*e + 1];
        float fc = fcb[e];
        float w0 = bd0 * fc, w1 = bd1 * fc, w2 = bd2 * fc;
        const float* g = G + (size_t)e * N_RBF;
        #pragma unroll
        for (int r = 0; r < N_RBF; r++) {
            float gr = g[r];
            w0 = fmaf(gr, wdr[r],           w0);
            w1 = fmaf(gr, wdr[N_RBF + r],   w1);
            w2 = fmaf(gr, wdr[2*N_RBF + r], w2);
        }
        size_t pj = (size_t)j * 384;
        float inv0 = phi[pj + f]       * w0;
        float inv1 = phi[pj + 128 + f] * w1;
        float inv2 = phi[pj + 256 + f] * w2;
        float ux = unit[3*e], uy = unit[3*e+1], uz = unit[3*e+2];
        size_t vj = (size_t)j * 384 + f;
        sacc += inv1;
        va0 = fmaf(inv0, vin[vj],       fmaf(ux, inv2, va0));
        va1 = fmaf(inv0, vin[vj + 128], fmaf(uy, inv2, va1));
        va2 = fmaf(inv0, vin[vj + 256], fmaf(uz, inv2, va2));
    }
    s[(size_t)i * FEAT + f] += sacc;
    size_t vi = (size_t)i * 384 + f;
    float n0 = vin[vi] + va0, n1 = vin[vi + 128] + va1, n2 = vin[vi + 256] + va2;
    ushort h;
    h = f2b(n0); vhi[vi]       = h; vlo[vi]       = f2b(n0 - b2f(h));
    h = f2b(n1); vhi[vi + 128] = h; vlo[vi + 128] = f2b(n1 - b2f(h));
    h = f2b(n2); vhi[vi + 256] = h; vlo[vi + 256] = f2b(n2 - b2f(h));
}

// ---------------- vnorm + concat -> CAT hi/lo ----------------
__global__ void k_vnorm_cat(const float* __restrict__ s, const float* __restrict__ vv,
                            ushort* __restrict__ chi, ushort* __restrict__ clo){
    int t = blockIdx.x * blockDim.x + threadIdx.x;
    if (t >= N_ATOMS * FEAT) return;
    int n = t >> 7, g = t & 127;
    size_t b = (size_t)n * 384 + g;
    float a0 = vv[b], a1 = vv[b + 128], a2 = vv[b + 256];
    float nr = sqrtf(a0*a0 + a1*a1 + a2*a2 + 1e-12f);
    float sv = s[t];
    size_t c0 = (size_t)n * 256 + g;
    ushort h;
    h = f2b(sv); chi[c0]       = h; clo[c0]       = f2b(sv - b2f(h));
    h = f2b(nr); chi[c0 + 128] = h; clo[c0 + 128] = f2b(nr - b2f(h));
}

// ---------------- gated update ----------------
__global__ void k_update(const float* __restrict__ uv, const float* __restrict__ vv,
                         const float* __restrict__ spl,
                         const ushort* __restrict__ vhi, const ushort* __restrict__ vlo,
                         float* __restrict__ s, float* __restrict__ v,
                         ushort* __restrict__ shi, ushort* __restrict__ slo){
    int t = blockIdx.x * blockDim.x + threadIdx.x;
    if (t >= N_ATOMS * FEAT) return;
    int n = t >> 7, g = t & 127;
    size_t sp = (size_t)n * 384 + g;
    float avv = spl[sp], asv = spl[sp + 128], ass = spl[sp + 256];
    float dot = 0.f;
    size_t b = (size_t)n * 384 + g;
    #pragma unroll
    for (int d = 0; d < 3; d++) {
        size_t idx = b + (size_t)d * 128;
        float u  = uv[idx];
        float w  = vv[idx];
        float vb = b2f(vhi[idx]) + b2f(vlo[idx]);
        dot = fmaf(u, w, dot);
        v[idx] = vb + u * avv;
    }
    float ns = s[t] + dot * asv + ass;
    s[t] = ns;
    ushort h = f2b(ns); shi[t] = h; slo[t] = f2b(ns - b2f(h));
}

// ---------------- host ----------------
struct Pair { ushort* hi; ushort* lo; };

static inline void gemm3(Pair A, Pair B, const float* bias,
                         int M, int K, int N, int Npad, int act,
                         float* Cf, Pair C, hipStream_t s){
    dim3 g(Npad / 64, (M + 127) / 128), b(256);
    switch (K) {
    case 64:  k_gemm3t<64> <<<g, b, 0, s>>>(A.hi, A.lo, B.hi, B.lo, bias, M, N, act, Cf, C.hi, C.lo); break;
    case 128: k_gemm3t<128><<<g, b, 0, s>>>(A.hi, A.lo, B.hi, B.lo, bias, M, N, act, Cf, C.hi, C.lo); break;
    case 256: k_gemm3t<256><<<g, b, 0, s>>>(A.hi, A.lo, B.hi, B.lo, bias, M, N, act, Cf, C.hi, C.lo); break;
    }
}

extern "C" void kernel_launch(void* const* d_in, const int* in_sizes, int n_in,
                              void* d_out, int out_size, void* d_ws, size_t ws_size,
                              hipStream_t stream) {
    float* ws = (float*)d_ws;
    int* flag = (int*)d_ws;
    const int* z    = (const int*)d_in[1];
    const int* nbrs = (const int*)d_in[2];

    k_detect<<<1, 64, 0, stream>>>((const unsigned int*)d_in[0], flag);

    P13 cp; {
        const int cidx[13] = {0,3,5,7,8,9,13,15,17,19,21,23,25};
        for (int i = 0; i < 13; i++) cp.p[i] = d_in[cidx[i]];
    }
    k_cvt_all<<<(100517 + 255)/256, 256, 0, stream>>>(cp, ws, flag);

    ushort* wb = (ushort*)(ws + H_WT);
    P11 wp; {
        const int widx[11] = {4,6,10,11,12,14,16,18,20,22,24};
        for (int i = 0; i < 11; i++) wp.p[i] = d_in[widx[i]];
    }
    k_wt_all<<<(WT_TOTAL + 255)/256, 256, 0, stream>>>(wp, wb, flag);

    // geometry + CSR
    k_geom<<<(N_EDGES+255)/256, 256, 0, stream>>>(ws + F_XYZ, nbrs, ws + F_FC, ws + F_UNIT, ws + F_G);
    int* cnt = (int*)(ws + F_CNT); int* row = (int*)(ws + F_ROW);
    int* cur = (int*)(ws + F_CUR); int* eid = (int*)(ws + F_EID);
    k_zero_i<<<(N_ATOMS+255)/256, 256, 0, stream>>>(cnt, N_ATOMS);
    k_hist<<<(N_EDGES+255)/256, 256, 0, stream>>>(nbrs, cnt);
    k_scan<<<1, 256, 0, stream>>>(cnt, row, cur);
    k_fill<<<(N_EDGES+255)/256, 256, 0, stream>>>(nbrs, cur, eid);

    float* S   = ws + F_S;
    float* V   = ws + F_V;
    float* PHI = ws + F_PHI;       // phi f32, then uv f32
    float* VV  = ws + F_VV;
    float* SPL = ws + F_SPL;
    auto WPW = [&](size_t off){ return Pair{ wb + off, wb + O_WTOT + off }; };
    Pair SHL { (ushort*)(ws + H_SHI),  (ushort*)(ws + H_SLO)  };
    Pair VHL { (ushort*)(ws + H_VHI),  (ushort*)(ws + H_VLO)  };
    Pair HA  { (ushort*)(ws + H_HAHI), (ushort*)(ws + H_HALO) };
    Pair HB  { (ushort*)(ws + H_HBHI), (ushort*)(ws + H_HBLO) };
    Pair AF  { (ushort*)(ws + H_AFHI), (ushort*)(ws + H_AFLO) };
    Pair CAT { (ushort*)(ws + F_SPL),  (ushort*)(ws + F_SPL) + (size_t)M20P*256 };
    Pair NOP { nullptr, nullptr };

    k_init_s<<<(N_ATOMS*FEAT+255)/256, 256, 0, stream>>>(ws + F_EMB, z, S, SHL.hi, SHL.lo);
    k_zero_f<<<(60000*FEAT+255)/256, 256, 0, stream>>>(V, 60000*FEAT);

    for (int l = 0; l < N_CONV; l++) {
        gemm3(SHL, WPW(O_W1T + l*16384), ws + F_B1 + l*128, N_ATOMS, 128, 128, 128, 1, nullptr, HA, stream);
        gemm3(HA,  WPW(O_W2T + l*49152), ws + F_B2 + l*384, N_ATOMS, 128, 384, 384, 0, PHI, NOP, stream);
        k_edge3<<<N_ATOMS, 128, 0, stream>>>(PHI, V, ws + F_UNIT, ws + F_FC, ws + F_G,
                                             nbrs, row, eid,
                                             ws + F_WD + (size_t)l*20*384, ws + F_BD + l*384,
                                             S, VHL.hi, VHL.lo);
        // uv + vv fused (shared A stream)
        {
            dim3 g(2, (60000 + 127) / 128), b(256);
            k_gemm3_dual<<<g, b, 0, stream>>>(VHL.hi, VHL.lo,
                                              wb + O_UT + l*16384, wb + O_WTOT + O_UT + l*16384,
                                              wb + O_VT + l*16384, wb + O_WTOT + O_VT + l*16384,
                                              60000, PHI, VV);
        }
        k_vnorm_cat<<<(N_ATOMS*FEAT+255)/256, 256, 0, stream>>>(S, VV, CAT.hi, CAT.lo);
        gemm3(CAT, WPW(O_WS1T + l*32768), ws + F_BS1 + l*128, N_ATOMS, 256, 128, 128, 1, nullptr, HB, stream);
        gemm3(HB,  WPW(O_WS2T + l*49152), ws + F_BS2 + l*384, N_ATOMS, 128, 384, 384, 0, SPL, NOP, stream);
        k_update<<<(N_ATOMS*FEAT+255)/256, 256, 0, stream>>>(PHI, VV, SPL, VHL.hi, VHL.lo,
                                                             S, V, SHL.hi, SHL.lo);
    }

    // readout
    gemm3(SHL, WPW(O_WR1T), ws + F_BR1, N_ATOMS, 128, 128, 128, 1, nullptr, HA, stream);
    gemm3(HA,  WPW(O_WR2T), ws + F_BR2, N_ATOMS, 128,  64,  64, 0, nullptr, AF, stream);
    gemm3(AF,  WPW(O_WF1T), ws + F_BF1, N_ATOMS,  64, 128, 128, 1, nullptr, HB, stream);
    gemm3(HB,  WPW(O_WF2T), ws + F_BF2, N_ATOMS, 128, 128, 128, 1, nullptr, HA, stream);
    gemm3(HA,  WPW(O_WF3T), ws + F_BF3, N_ATOMS, 128, N_OUT_, 64, 0, ws + F_OUT, NOP, stream);

    k_store_out<<<(N_ATOMS*N_OUT_+255)/256, 256, 0, stream>>>(ws + F_OUT, d_out, N_ATOMS*N_OUT_, flag);
}

// Round 6
// 1360.983 us; speedup vs baseline: 3.0335x; 1.0614x over previous
//
#include <hip/hip_runtime.h>
#include <hip/hip_bf16.h>
#include <math.h>

#define N_ATOMS 20000
#define N_EDGES 320000
#define FEAT 128
#define N_RBF 20
#define N_CONV 3
#define N_OUT_ 5
#define PI_F 3.14159265358979f
#define M20P 20032
#define M60P 60032

typedef unsigned short ushort;
typedef __bf16 bf16x8 __attribute__((ext_vector_type(8)));
typedef float f32x4 __attribute__((ext_vector_type(4)));

__device__ __forceinline__ float b2f(ushort u){ return __uint_as_float(((unsigned)u) << 16); }
__device__ __forceinline__ ushort f2b(float x){
    unsigned u = __float_as_uint(x);
    return (ushort)((u + 0x7FFFu + ((u >> 16) & 1u)) >> 16);   // RNE
}

// ---------------- workspace layout (float slots) ----------------
constexpr size_t rnd64(size_t x){ return (x + 63) & ~size_t(63); }
constexpr size_t F_XYZ  = 64;                                  // flag at ws[0]
constexpr size_t F_EMB  = rnd64(F_XYZ + 60000);
constexpr size_t F_B1   = rnd64(F_EMB + 12800);
constexpr size_t F_B2   = rnd64(F_B1  + 3*128);
constexpr size_t F_WD   = rnd64(F_B2  + 3*384);
constexpr size_t F_BD   = rnd64(F_WD  + 3*20*384);
constexpr size_t F_BS1  = rnd64(F_BD  + 3*384);
constexpr size_t F_BS2  = rnd64(F_BS1 + 3*128);
constexpr size_t F_BR1  = rnd64(F_BS2 + 3*384);
constexpr size_t F_BR2  = rnd64(F_BR1 + 128);
constexpr size_t F_BF1  = rnd64(F_BR2 + 64);
constexpr size_t F_BF2  = rnd64(F_BF1 + 128);
constexpr size_t F_BF3  = rnd64(F_BF2 + 128);
constexpr size_t F_CNT  = rnd64(F_BF3 + 8);                    // int
constexpr size_t F_ROW  = rnd64(F_CNT  + N_ATOMS);             // int, +1
constexpr size_t F_CUR  = rnd64(F_ROW  + N_ATOMS + 1);         // int
constexpr size_t F_EID  = rnd64(F_CUR  + N_ATOMS);             // int
constexpr size_t F_EJ   = rnd64(F_EID  + N_EDGES);             // int, CSR-ordered j
constexpr size_t F_EREC = rnd64(F_EJ   + N_EDGES);             // 24 floats/edge, CSR order
constexpr size_t F_S    = rnd64(F_EREC + (size_t)N_EDGES*24);
constexpr size_t F_V    = rnd64(F_S    + (size_t)N_ATOMS*FEAT);
constexpr size_t F_PHI  = rnd64(F_V    + (size_t)60000*FEAT);     // phi f32, later uv f32
constexpr size_t F_VV   = rnd64(F_PHI  + (size_t)N_ATOMS*384);
constexpr size_t F_SPL  = rnd64(F_VV   + (size_t)60000*FEAT);     // split f32; CAT hi/lo aliases
constexpr size_t F_OUT  = rnd64(F_SPL  + (size_t)N_ATOMS*384);
// bf16 hi/lo pair buffers (slot counts = elems/2)
constexpr size_t H_SHI  = rnd64(F_OUT  + N_ATOMS*N_OUT_);
constexpr size_t H_SLO  = rnd64(H_SHI  + (size_t)M20P*128/2);
constexpr size_t H_VHI  = rnd64(H_SLO  + (size_t)M20P*128/2);
constexpr size_t H_VLO  = rnd64(H_VHI  + (size_t)M60P*128/2);
constexpr size_t H_HAHI = rnd64(H_VLO  + (size_t)M60P*128/2);
constexpr size_t H_HALO = rnd64(H_HAHI + (size_t)M20P*128/2);
constexpr size_t H_HBHI = rnd64(H_HALO + (size_t)M20P*128/2);
constexpr size_t H_HBLO = rnd64(H_HBHI + (size_t)M20P*128/2);
constexpr size_t H_AFHI = rnd64(H_HBLO + (size_t)M20P*128/2);
constexpr size_t H_AFLO = rnd64(H_AFHI + (size_t)M20P*64/2);
constexpr size_t H_WT   = rnd64(H_AFLO + (size_t)M20P*64/2);
// weight offsets (ushort elems within hi half; lo = +O_WTOT)
constexpr size_t O_W1T=0, O_W2T=49152, O_UT=196608, O_VT=245760, O_WS1T=294912,
                 O_WS2T=393216, O_WR1T=540672, O_WR2T=557056, O_WF1T=565248,
                 O_WF2T=573440, O_WF3T=589824, O_WTOT=598016;

// ---------------- dtype detection ----------------
__global__ void k_detect(const unsigned int* __restrict__ bits, int* flag){
    __shared__ int cnt;
    if (threadIdx.x == 0) cnt = 0;
    __syncthreads();
    unsigned int lo = bits[threadIdx.x] & 0xFFFFu;
    if (lo >= 0x3000u && lo <= 0x4100u) atomicAdd(&cnt, 1);
    __syncthreads();
    if (threadIdx.x == 0) *flag = (cnt >= 48) ? 1 : 0;
}

// ---------------- mega f32-convert (13 segments, 1 launch) ----------------
struct P13 { const void* p[13]; };
__global__ void k_cvt_all(P13 sp, float* __restrict__ ws, const int* __restrict__ flag){
    constexpr int   NSEG = 13;
    constexpr int    SZ[NSEG] = {60000,12800,384,1152,23040,1152,384,1152,128,64,128,128,5};
    constexpr size_t DO_[NSEG]= {F_XYZ,F_EMB,F_B1,F_B2,F_WD,F_BD,F_BS1,F_BS2,F_BR1,F_BR2,F_BF1,F_BF2,F_BF3};
    int t = blockIdx.x * blockDim.x + threadIdx.x;
    int bf = *flag;
    #pragma unroll
    for (int s = 0; s < NSEG; s++){
        if (t < SZ[s]){
            float v = bf ? b2f(((const ushort*)sp.p[s])[t]) : ((const float*)sp.p[s])[t];
            ws[DO_[s] + t] = v;
            return;
        }
        t -= SZ[s];
    }
}

// ---------------- mega weight transpose hi/lo (23 segments, 1 launch) ----------------
struct P11 { const void* p[11]; };
__global__ void k_wt_all(P11 sp, ushort* __restrict__ wb, const int* __restrict__ flag){
    constexpr int NSEG = 23;
    constexpr int SRC[NSEG]  = {0,1,2,3,4,5, 0,1,2,3,4,5, 0,1,2,3,4,5, 6,7,8,9,10};
    constexpr int SOFF[NSEG] = {0,0,0,0,0,0, 16384,49152,16384,16384,32768,49152,
                                32768,98304,32768,32768,65536,98304, 0,0,0,0,0};
    constexpr size_t DOFF[NSEG]={O_W1T,O_W2T,O_UT,O_VT,O_WS1T,O_WS2T,
                                 O_W1T+16384,O_W2T+49152,O_UT+16384,O_VT+16384,O_WS1T+32768,O_WS2T+49152,
                                 O_W1T+32768,O_W2T+98304,O_UT+32768,O_VT+32768,O_WS1T+65536,O_WS2T+98304,
                                 O_WR1T,O_WR2T,O_WF1T,O_WF2T,O_WF3T};
    constexpr int KK[NSEG]   = {128,128,128,128,256,128, 128,128,128,128,256,128,
                                128,128,128,128,256,128, 128,128,64,128,128};
    constexpr int NN[NSEG]   = {128,384,128,128,128,384, 128,384,128,128,128,384,
                                128,384,128,128,128,384, 128,64,128,128,5};
    constexpr int NP[NSEG]   = {128,384,128,128,128,384, 128,384,128,128,128,384,
                                128,384,128,128,128,384, 128,64,128,128,64};
    int t = blockIdx.x * blockDim.x + threadIdx.x;
    int bf = *flag;
    #pragma unroll
    for (int s = 0; s < NSEG; s++){
        int tot = NP[s] * KK[s];
        if (t < tot){
            int n = t / KK[s], k = t & (KK[s] - 1);
            ushort hi = 0, lo = 0;
            if (n < NN[s]){
                int si = SOFF[s] + k * NN[s] + n;
                float w = bf ? b2f(((const ushort*)sp.p[SRC[s]])[si])
                             : ((const float*)sp.p[SRC[s]])[si];
                hi = f2b(w); lo = f2b(w - b2f(hi));
            }
            wb[DOFF[s] + t] = hi;
            wb[O_WTOT + DOFF[s] + t] = lo;
            return;
        }
        t -= tot;
    }
}
constexpr int WT_TOTAL = 598016;

__global__ void k_store_out(const float* __restrict__ src, void* __restrict__ dst, int n,
                            const int* __restrict__ flag){
    int t = blockIdx.x * blockDim.x + threadIdx.x;
    if (t >= n) return;
    float v = src[t];
    if (*flag) ((ushort*)dst)[t] = f2b(v);
    else       ((float*)dst)[t] = v;
}

// ---------------- utility ----------------
__global__ void k_zero_f(float* p, int n){
    int t = blockIdx.x * blockDim.x + threadIdx.x;
    if (t < n) p[t] = 0.f;
}
__global__ void k_zero_i(int* p, int n){
    int t = blockIdx.x * blockDim.x + threadIdx.x;
    if (t < n) p[t] = 0;
}
__global__ void k_init_s(const float* __restrict__ embed, const int* __restrict__ z,
                         float* __restrict__ s, ushort* __restrict__ shi,
                         ushort* __restrict__ slo){
    int t = blockIdx.x * blockDim.x + threadIdx.x;
    if (t >= N_ATOMS * FEAT) return;
    int n = t >> 7, f = t & 127;
    float v = embed[z[n] * FEAT + f];
    s[t] = v;
    ushort h = f2b(v); shi[t] = h; slo[t] = f2b(v - b2f(h));
}

// ---------------- CSR build ----------------
__global__ void k_hist(const int* __restrict__ nbrs, int* __restrict__ cnt){
    int e = blockIdx.x * blockDim.x + threadIdx.x;
    if (e < N_EDGES) atomicAdd(&cnt[nbrs[2*e]], 1);
}
__global__ void k_scan(const int* __restrict__ cnt, int* __restrict__ row, int* __restrict__ cur){
    __shared__ int ls[256];
    int t = threadIdx.x, base = t * 80;
    int s = 0;
    for (int k = 0; k < 80; k++){ int i = base + k; if (i < N_ATOMS) s += cnt[i]; }
    ls[t] = s; __syncthreads();
    for (int off = 1; off < 256; off <<= 1){
        int v = (t >= off) ? ls[t - off] : 0;
        __syncthreads();
        ls[t] += v;
        __syncthreads();
    }
    int run = ls[t] - s;
    for (int k = 0; k < 80; k++){
        int i = base + k;
        if (i < N_ATOMS){ row[i] = run; cur[i] = run; run += cnt[i]; }
    }
    if (t == 255) row[N_ATOMS] = ls[255];
}
__global__ void k_fill(const int* __restrict__ nbrs, int* __restrict__ cur, int* __restrict__ eid){
    int e = blockIdx.x * blockDim.x + threadIdx.x;
    if (e >= N_EDGES) return;
    int p = atomicAdd(&cur[nbrs[2*e]], 1);
    eid[p] = e;
}

// ---------------- geometry in CSR order: EJ + packed 24-float record --------
// rec = {fc, ux, uy, uz, G[0..19]}  (G = sin((r+1)b)/d * fc via Chebyshev)
__global__ void k_geom_csr(const float* __restrict__ xyz, const int* __restrict__ nbrs,
                           const int* __restrict__ eid,
                           int* __restrict__ EJ, float* __restrict__ EREC){
    int idx = blockIdx.x * blockDim.x + threadIdx.x;
    if (idx >= N_EDGES) return;
    int e = eid[idx];
    int i = nbrs[2*e], j = nbrs[2*e+1];
    float rx = xyz[3*j]   - xyz[3*i];
    float ry = xyz[3*j+1] - xyz[3*i+1];
    float rz = xyz[3*j+2] - xyz[3*i+2];
    float d  = sqrtf(rx*rx + ry*ry + rz*rz + 1e-12f);
    float inv = 1.0f / d;
    float b  = PI_F * d * 0.2f;
    float sb = sinf(b), cb = cosf(b);
    float fc = (d < 5.0f) ? 0.5f * (cb + 1.0f) : 0.0f;
    float scale = inv * fc, c2 = 2.0f * cb;
    EJ[idx] = j;
    float* rec = EREC + (size_t)idx * 24;
    rec[0] = fc; rec[1] = rx*inv; rec[2] = ry*inv; rec[3] = rz*inv;
    float sp = 0.f, sc = sb;
    #pragma unroll
    for (int r = 0; r < N_RBF; r++){
        rec[4 + r] = sc * scale;
        float sn = c2 * sc - sp;
        sp = sc; sc = sn;
    }
}

// ---------------- split-bf16 MFMA GEMM, fat wave tile 32x64 ----------------
template<int KT>
__global__ __launch_bounds__(256) void k_gemm3t(
    const ushort* __restrict__ Ahi, const ushort* __restrict__ Alo,
    const ushort* __restrict__ Bthi, const ushort* __restrict__ Btlo,
    const float* __restrict__ bias, int M, int N, int act,
    float* __restrict__ Cf, ushort* __restrict__ Chi, ushort* __restrict__ Clo)
{
    int wave = threadIdx.x >> 6, lane = threadIdx.x & 63;
    int l15 = lane & 15, quad = lane >> 4;
    int m0 = blockIdx.y * 128 + wave * 32;
    int n0 = blockIdx.x * 64;
    const ushort* aph = Ahi  + (size_t)(m0 + l15) * KT + quad * 8;
    const ushort* apl = Alo  + (size_t)(m0 + l15) * KT + quad * 8;
    const ushort* bph = Bthi + (size_t)(n0 + l15) * KT + quad * 8;
    const ushort* bpl = Btlo + (size_t)(n0 + l15) * KT + quad * 8;
    f32x4 acc[2][4];
    #pragma unroll
    for (int r = 0; r < 2; r++)
        #pragma unroll
        for (int c = 0; c < 4; c++) acc[r][c] = (f32x4){0.f, 0.f, 0.f, 0.f};
    #pragma unroll
    for (int k0 = 0; k0 < KT; k0 += 32) {
        bf16x8 ah0 = *reinterpret_cast<const bf16x8*>(aph + k0);
        bf16x8 al0 = *reinterpret_cast<const bf16x8*>(apl + k0);
        bf16x8 ah1 = *reinterpret_cast<const bf16x8*>(aph + (size_t)16 * KT + k0);
        bf16x8 al1 = *reinterpret_cast<const bf16x8*>(apl + (size_t)16 * KT + k0);
        #pragma unroll
        for (int c = 0; c < 4; c++) {
            bf16x8 bh = *reinterpret_cast<const bf16x8*>(bph + (size_t)c * 16 * KT + k0);
            bf16x8 bl = *reinterpret_cast<const bf16x8*>(bpl + (size_t)c * 16 * KT + k0);
            acc[0][c] = __builtin_amdgcn_mfma_f32_16x16x32_bf16(al0, bh, acc[0][c], 0, 0, 0);
            acc[0][c] = __builtin_amdgcn_mfma_f32_16x16x32_bf16(ah0, bl, acc[0][c], 0, 0, 0);
            acc[0][c] = __builtin_amdgcn_mfma_f32_16x16x32_bf16(ah0, bh, acc[0][c], 0, 0, 0);
            acc[1][c] = __builtin_amdgcn_mfma_f32_16x16x32_bf16(al1, bh, acc[1][c], 0, 0, 0);
            acc[1][c] = __builtin_amdgcn_mfma_f32_16x16x32_bf16(ah1, bl, acc[1][c], 0, 0, 0);
            acc[1][c] = __builtin_amdgcn_mfma_f32_16x16x32_bf16(ah1, bh, acc[1][c], 0, 0, 0);
        }
    }
    #pragma unroll
    for (int rr = 0; rr < 2; rr++) {
        int row_base = m0 + rr * 16 + quad * 4;
        #pragma unroll
        for (int c = 0; c < 4; c++) {
            int col = n0 + c * 16 + l15;
            #pragma unroll
            for (int r = 0; r < 4; r++) {
                int row = row_base + r;
                if (row < M && col < N) {
                    float v = acc[rr][c][r];
                    if (bias) v += bias[col];
                    if (act)  v = v / (1.f + expf(-v));
                    size_t idx = (size_t)row * N + col;
                    if (Cf)  Cf[idx] = v;
                    if (Chi) { ushort h = f2b(v); Chi[idx] = h; Clo[idx] = f2b(v - b2f(h)); }
                }
            }
        }
    }
}

// ---------------- dual GEMM: C1 = A@B1^T, C2 = A@B2^T (shared A read) -------
__global__ __launch_bounds__(256) void k_gemm3_dual(
    const ushort* __restrict__ Ahi, const ushort* __restrict__ Alo,
    const ushort* __restrict__ B1hi, const ushort* __restrict__ B1lo,
    const ushort* __restrict__ B2hi, const ushort* __restrict__ B2lo,
    int M, float* __restrict__ C1, float* __restrict__ C2)
{
    constexpr int KT = 128, N = 128;
    int wave = threadIdx.x >> 6, lane = threadIdx.x & 63;
    int l15 = lane & 15, quad = lane >> 4;
    int m0 = blockIdx.y * 128 + wave * 32;
    int n0 = blockIdx.x * 64;
    const ushort* aph = Ahi  + (size_t)(m0 + l15) * KT + quad * 8;
    const ushort* apl = Alo  + (size_t)(m0 + l15) * KT + quad * 8;
    const ushort* b1h = B1hi + (size_t)(n0 + l15) * KT + quad * 8;
    const ushort* b1l = B1lo + (size_t)(n0 + l15) * KT + quad * 8;
    const ushort* b2h = B2hi + (size_t)(n0 + l15) * KT + quad * 8;
    const ushort* b2l = B2lo + (size_t)(n0 + l15) * KT + quad * 8;
    f32x4 acc1[2][4], acc2[2][4];
    #pragma unroll
    for (int r = 0; r < 2; r++)
        #pragma unroll
        for (int c = 0; c < 4; c++) {
            acc1[r][c] = (f32x4){0.f,0.f,0.f,0.f};
            acc2[r][c] = (f32x4){0.f,0.f,0.f,0.f};
        }
    #pragma unroll
    for (int k0 = 0; k0 < KT; k0 += 32) {
        bf16x8 ah0 = *reinterpret_cast<const bf16x8*>(aph + k0);
        bf16x8 al0 = *reinterpret_cast<const bf16x8*>(apl + k0);
        bf16x8 ah1 = *reinterpret_cast<const bf16x8*>(aph + (size_t)16 * KT + k0);
        bf16x8 al1 = *reinterpret_cast<const bf16x8*>(apl + (size_t)16 * KT + k0);
        #pragma unroll
        for (int c = 0; c < 4; c++) {
            bf16x8 bh = *reinterpret_cast<const bf16x8*>(b1h + (size_t)c * 16 * KT + k0);
            bf16x8 bl = *reinterpret_cast<const bf16x8*>(b1l + (size_t)c * 16 * KT + k0);
            acc1[0][c] = __builtin_amdgcn_mfma_f32_16x16x32_bf16(al0, bh, acc1[0][c], 0, 0, 0);
            acc1[0][c] = __builtin_amdgcn_mfma_f32_16x16x32_bf16(ah0, bl, acc1[0][c], 0, 0, 0);
            acc1[0][c] = __builtin_amdgcn_mfma_f32_16x16x32_bf16(ah0, bh, acc1[0][c], 0, 0, 0);
            acc1[1][c] = __builtin_amdgcn_mfma_f32_16x16x32_bf16(al1, bh, acc1[1][c], 0, 0, 0);
            acc1[1][c] = __builtin_amdgcn_mfma_f32_16x16x32_bf16(ah1, bl, acc1[1][c], 0, 0, 0);
            acc1[1][c] = __builtin_amdgcn_mfma_f32_16x16x32_bf16(ah1, bh, acc1[1][c], 0, 0, 0);
        }
        #pragma unroll
        for (int c = 0; c < 4; c++) {
            bf16x8 bh = *reinterpret_cast<const bf16x8*>(b2h + (size_t)c * 16 * KT + k0);
            bf16x8 bl = *reinterpret_cast<const bf16x8*>(b2l + (size_t)c * 16 * KT + k0);
            acc2[0][c] = __builtin_amdgcn_mfma_f32_16x16x32_bf16(al0, bh, acc2[0][c], 0, 0, 0);
            acc2[0][c] = __builtin_amdgcn_mfma_f32_16x16x32_bf16(ah0, bl, acc2[0][c], 0, 0, 0);
            acc2[0][c] = __builtin_amdgcn_mfma_f32_16x16x32_bf16(ah0, bh, acc2[0][c], 0, 0, 0);
            acc2[1][c] = __builtin_amdgcn_mfma_f32_16x16x32_bf16(al1, bh, acc2[1][c], 0, 0, 0);
            acc2[1][c] = __builtin_amdgcn_mfma_f32_16x16x32_bf16(ah1, bl, acc2[1][c], 0, 0, 0);
            acc2[1][c] = __builtin_amdgcn_mfma_f32_16x16x32_bf16(ah1, bh, acc2[1][c], 0, 0, 0);
        }
    }
    #pragma unroll
    for (int rr = 0; rr < 2; rr++) {
        int row_base = m0 + rr * 16 + quad * 4;
        #pragma unroll
        for (int c = 0; c < 4; c++) {
            int col = n0 + c * 16 + l15;
            #pragma unroll
            for (int r = 0; r < 4; r++) {
                int row = row_base + r;
                if (row < M) {
                    size_t idx = (size_t)row * N + col;
                    C1[idx] = acc1[rr][c][r];
                    C2[idx] = acc2[rr][c][r];
                }
            }
        }
    }
}

// ---------------- edge gather-reduce v4: CSR records, 2x unroll -------------
__global__ __launch_bounds__(128) void k_edge4(
    const float* __restrict__ phi, const float* __restrict__ vin,
    const int* __restrict__ EJ, const float* __restrict__ EREC,
    const int* __restrict__ row,
    const float* __restrict__ Wd, const float* __restrict__ bd,
    float* __restrict__ s, ushort* __restrict__ vhi, ushort* __restrict__ vlo)
{
    int i = blockIdx.x, f = threadIdx.x;
    float wdr[3 * N_RBF];
    #pragma unroll
    for (int r = 0; r < N_RBF; r++) {
        wdr[r]           = Wd[r*384 + f];
        wdr[N_RBF + r]   = Wd[r*384 + 128 + f];
        wdr[2*N_RBF + r] = Wd[r*384 + 256 + f];
    }
    float bd0 = bd[f], bd1 = bd[128 + f], bd2 = bd[256 + f];
    float sacc = 0.f, va0 = 0.f, va1 = 0.f, va2 = 0.f;
    int beg = row[i], end = row[i + 1];

    auto body = [&](int idx){
        int j = EJ[idx];
        const float4* rq = reinterpret_cast<const float4*>(EREC + (size_t)idx * 24);
        float4 q0 = rq[0], q1 = rq[1], q2 = rq[2], q3 = rq[3], q4 = rq[4], q5 = rq[5];
        float g[20] = {q1.x,q1.y,q1.z,q1.w, q2.x,q2.y,q2.z,q2.w,
                       q3.x,q3.y,q3.z,q3.w, q4.x,q4.y,q4.z,q4.w,
                       q5.x,q5.y,q5.z,q5.w};
        float w0 = bd0 * q0.x, w1 = bd1 * q0.x, w2 = bd2 * q0.x;
        #pragma unroll
        for (int r = 0; r < N_RBF; r++) {
            w0 = fmaf(g[r], wdr[r],           w0);
            w1 = fmaf(g[r], wdr[N_RBF + r],   w1);
            w2 = fmaf(g[r], wdr[2*N_RBF + r], w2);
        }
        size_t pj = (size_t)j * 384;
        float inv0 = phi[pj + f]       * w0;
        float inv1 = phi[pj + 128 + f] * w1;
        float inv2 = phi[pj + 256 + f] * w2;
        size_t vj = (size_t)j * 384 + f;
        sacc += inv1;
        va0 = fmaf(inv0, vin[vj],       fmaf(q0.y, inv2, va0));
        va1 = fmaf(inv0, vin[vj + 128], fmaf(q0.z, inv2, va1));
        va2 = fmaf(inv0, vin[vj + 256], fmaf(q0.w, inv2, va2));
    };

    int idx = beg;
    for (; idx + 1 < end; idx += 2) { body(idx); body(idx + 1); }
    if (idx < end) body(idx);

    s[(size_t)i * FEAT + f] += sacc;
    size_t vi = (size_t)i * 384 + f;
    float n0 = vin[vi] + va0, n1 = vin[vi + 128] + va1, n2 = vin[vi + 256] + va2;
    ushort h;
    h = f2b(n0); vhi[vi]       = h; vlo[vi]       = f2b(n0 - b2f(h));
    h = f2b(n1); vhi[vi + 128] = h; vlo[vi + 128] = f2b(n1 - b2f(h));
    h = f2b(n2); vhi[vi + 256] = h; vlo[vi + 256] = f2b(n2 - b2f(h));
}

// ---------------- vnorm + concat -> CAT hi/lo ----------------
__global__ void k_vnorm_cat(const float* __restrict__ s, const float* __restrict__ vv,
                            ushort* __restrict__ chi, ushort* __restrict__ clo){
    int t = blockIdx.x * blockDim.x + threadIdx.x;
    if (t >= N_ATOMS * FEAT) return;
    int n = t >> 7, g = t & 127;
    size_t b = (size_t)n * 384 + g;
    float a0 = vv[b], a1 = vv[b + 128], a2 = vv[b + 256];
    float nr = sqrtf(a0*a0 + a1*a1 + a2*a2 + 1e-12f);
    float sv = s[t];
    size_t c0 = (size_t)n * 256 + g;
    ushort h;
    h = f2b(sv); chi[c0]       = h; clo[c0]       = f2b(sv - b2f(h));
    h = f2b(nr); chi[c0 + 128] = h; clo[c0 + 128] = f2b(nr - b2f(h));
}

// ---------------- gated update ----------------
__global__ void k_update(const float* __restrict__ uv, const float* __restrict__ vv,
                         const float* __restrict__ spl,
                         const ushort* __restrict__ vhi, const ushort* __restrict__ vlo,
                         float* __restrict__ s, float* __restrict__ v,
                         ushort* __restrict__ shi, ushort* __restrict__ slo){
    int t = blockIdx.x * blockDim.x + threadIdx.x;
    if (t >= N_ATOMS * FEAT) return;
    int n = t >> 7, g = t & 127;
    size_t sp = (size_t)n * 384 + g;
    float avv = spl[sp], asv = spl[sp + 128], ass = spl[sp + 256];
    float dot = 0.f;
    size_t b = (size_t)n * 384 + g;
    #pragma unroll
    for (int d = 0; d < 3; d++) {
        size_t idx = b + (size_t)d * 128;
        float u  = uv[idx];
        float w  = vv[idx];
        float vb = b2f(vhi[idx]) + b2f(vlo[idx]);
        dot = fmaf(u, w, dot);
        v[idx] = vb + u * avv;
    }
    float ns = s[t] + dot * asv + ass;
    s[t] = ns;
    ushort h = f2b(ns); shi[t] = h; slo[t] = f2b(ns - b2f(h));
}

// ---------------- host ----------------
struct Pair { ushort* hi; ushort* lo; };

static inline void gemm3(Pair A, Pair B, const float* bias,
                         int M, int K, int N, int Npad, int act,
                         float* Cf, Pair C, hipStream_t s){
    dim3 g(Npad / 64, (M + 127) / 128), b(256);
    switch (K) {
    case 64:  k_gemm3t<64> <<<g, b, 0, s>>>(A.hi, A.lo, B.hi, B.lo, bias, M, N, act, Cf, C.hi, C.lo); break;
    case 128: k_gemm3t<128><<<g, b, 0, s>>>(A.hi, A.lo, B.hi, B.lo, bias, M, N, act, Cf, C.hi, C.lo); break;
    case 256: k_gemm3t<256><<<g, b, 0, s>>>(A.hi, A.lo, B.hi, B.lo, bias, M, N, act, Cf, C.hi, C.lo); break;
    }
}

extern "C" void kernel_launch(void* const* d_in, const int* in_sizes, int n_in,
                              void* d_out, int out_size, void* d_ws, size_t ws_size,
                              hipStream_t stream) {
    float* ws = (float*)d_ws;
    int* flag = (int*)d_ws;
    const int* z    = (const int*)d_in[1];
    const int* nbrs = (const int*)d_in[2];

    k_detect<<<1, 64, 0, stream>>>((const unsigned int*)d_in[0], flag);

    P13 cp; {
        const int cidx[13] = {0,3,5,7,8,9,13,15,17,19,21,23,25};
        for (int i = 0; i < 13; i++) cp.p[i] = d_in[cidx[i]];
    }
    k_cvt_all<<<(100517 + 255)/256, 256, 0, stream>>>(cp, ws, flag);

    ushort* wb = (ushort*)(ws + H_WT);
    P11 wp; {
        const int widx[11] = {4,6,10,11,12,14,16,18,20,22,24};
        for (int i = 0; i < 11; i++) wp.p[i] = d_in[widx[i]];
    }
    k_wt_all<<<(WT_TOTAL + 255)/256, 256, 0, stream>>>(wp, wb, flag);

    // CSR build + CSR-ordered geometry records
    int* cnt = (int*)(ws + F_CNT); int* row = (int*)(ws + F_ROW);
    int* cur = (int*)(ws + F_CUR); int* eid = (int*)(ws + F_EID);
    int* EJ  = (int*)(ws + F_EJ);  float* EREC = ws + F_EREC;
    k_zero_i<<<(N_ATOMS+255)/256, 256, 0, stream>>>(cnt, N_ATOMS);
    k_hist<<<(N_EDGES+255)/256, 256, 0, stream>>>(nbrs, cnt);
    k_scan<<<1, 256, 0, stream>>>(cnt, row, cur);
    k_fill<<<(N_EDGES+255)/256, 256, 0, stream>>>(nbrs, cur, eid);
    k_geom_csr<<<(N_EDGES+255)/256, 256, 0, stream>>>(ws + F_XYZ, nbrs, eid, EJ, EREC);

    float* S   = ws + F_S;
    float* V   = ws + F_V;
    float* PHI = ws + F_PHI;       // phi f32, then uv f32
    float* VV  = ws + F_VV;
    float* SPL = ws + F_SPL;
    auto WPW = [&](size_t off){ return Pair{ wb + off, wb + O_WTOT + off }; };
    Pair SHL { (ushort*)(ws + H_SHI),  (ushort*)(ws + H_SLO)  };
    Pair VHL { (ushort*)(ws + H_VHI),  (ushort*)(ws + H_VLO)  };
    Pair HA  { (ushort*)(ws + H_HAHI), (ushort*)(ws + H_HALO) };
    Pair HB  { (ushort*)(ws + H_HBHI), (ushort*)(ws + H_HBLO) };
    Pair AF  { (ushort*)(ws + H_AFHI), (ushort*)(ws + H_AFLO) };
    Pair CAT { (ushort*)(ws + F_SPL),  (ushort*)(ws + F_SPL) + (size_t)M20P*256 };
    Pair NOP { nullptr, nullptr };

    k_init_s<<<(N_ATOMS*FEAT+255)/256, 256, 0, stream>>>(ws + F_EMB, z, S, SHL.hi, SHL.lo);
    k_zero_f<<<(60000*FEAT+255)/256, 256, 0, stream>>>(V, 60000*FEAT);

    for (int l = 0; l < N_CONV; l++) {
        gemm3(SHL, WPW(O_W1T + l*16384), ws + F_B1 + l*128, N_ATOMS, 128, 128, 128, 1, nullptr, HA, stream);
        gemm3(HA,  WPW(O_W2T + l*49152), ws + F_B2 + l*384, N_ATOMS, 128, 384, 384, 0, PHI, NOP, stream);
        k_edge4<<<N_ATOMS, 128, 0, stream>>>(PHI, V, EJ, EREC, row,
                                             ws + F_WD + (size_t)l*20*384, ws + F_BD + l*384,
                                             S, VHL.hi, VHL.lo);
        {
            dim3 g(2, (60000 + 127) / 128), b(256);
            k_gemm3_dual<<<g, b, 0, stream>>>(VHL.hi, VHL.lo,
                                              wb + O_UT + l*16384, wb + O_WTOT + O_UT + l*16384,
                                              wb + O_VT + l*16384, wb + O_WTOT + O_VT + l*16384,
                                              60000, PHI, VV);
        }
        k_vnorm_cat<<<(N_ATOMS*FEAT+255)/256, 256, 0, stream>>>(S, VV, CAT.hi, CAT.lo);
        gemm3(CAT, WPW(O_WS1T + l*32768), ws + F_BS1 + l*128, N_ATOMS, 256, 128, 128, 1, nullptr, HB, stream);
        gemm3(HB,  WPW(O_WS2T + l*49152), ws + F_BS2 + l*384, N_ATOMS, 128, 384, 384, 0, SPL, NOP, stream);
        k_update<<<(N_ATOMS*FEAT+255)/256, 256, 0, stream>>>(PHI, VV, SPL, VHL.hi, VHL.lo,
                                                             S, V, SHL.hi, SHL.lo);
    }

    // readout
    gemm3(SHL, WPW(O_WR1T), ws + F_BR1, N_ATOMS, 128, 128, 128, 1, nullptr, HA, stream);
    gemm3(HA,  WPW(O_WR2T), ws + F_BR2, N_ATOMS, 128,  64,  64, 0, nullptr, AF, stream);
    gemm3(AF,  WPW(O_WF1T), ws + F_BF1, N_ATOMS,  64, 128, 128, 1, nullptr, HB, stream);
    gemm3(HB,  WPW(O_WF2T), ws + F_BF2, N_ATOMS, 128, 128, 128, 1, nullptr, HA, stream);
    gemm3(HA,  WPW(O_WF3T), ws + F_BF3, N_ATOMS, 128, N_OUT_, 64, 0, ws + F_OUT, NOP, stream);

    k_store_out<<<(N_ATOMS*N_OUT_+255)/256, 256, 0, stream>>>(ws + F_OUT, d_out, N_ATOMS*N_OUT_, flag);
}